// Round 11
// baseline (469.005 us; speedup 1.0000x reference)
//
#include <hip/hip_runtime.h>
#include <hip/hip_fp16.h>

typedef _Float16 f16;
typedef __attribute__((ext_vector_type(2))) _Float16 f16x2;
typedef __attribute__((ext_vector_type(4))) _Float16 f16x4v;
typedef __attribute__((ext_vector_type(8))) _Float16 f16x8;
typedef __attribute__((ext_vector_type(4))) float f32x4;
typedef __attribute__((ext_vector_type(4))) int i32x4;

#define DEV __device__ __forceinline__

static constexpr int S_ = 2048;
static constexpr int D_ = 2048;
static constexpr int H_ = 16;
static constexpr int HD_ = 128;
static constexpr int B_ = 4;
static constexpr int QKV_ST = 6144;  // fused qkv row stride (Q|K|V)

typedef const __attribute__((address_space(1))) void* gptr_t;
typedef __attribute__((address_space(3))) void* lptr_t;

// async global->LDS, 16B per lane. LDS dest must be wave-uniform; HW writes
// dest + lane*16 (m104 semantics). Compiler manages m0.
DEV void gl_lds16(const void* gsrc, void* lds) {
  __builtin_amdgcn_global_load_lds((gptr_t)gsrc, (lptr_t)lds, 16, 0, 0);
}

// f32 pair -> packed f16x2 bits (v_cvt_pkrtz_f16_f32)
DEV int cvt_pk_i32(float a, float b) {
  return __builtin_bit_cast(int, __builtin_amdgcn_cvt_pkrtz(a, b));
}

__global__ __launch_bounds__(256) void cvt_f32_to_f16(const float* __restrict__ in,
                                                      f16* __restrict__ out, long n) {
  long i0 = ((long)blockIdx.x * 256 + threadIdx.x) * 4;
  long stride = (long)gridDim.x * 256 * 4;
  for (long i = i0; i < n; i += stride) {
    float4 v = *(const float4*)(in + i);
    f16x4v o;
    o[0] = (f16)v.x; o[1] = (f16)v.y; o[2] = (f16)v.z; o[3] = (f16)v.w;
    *(f16x4v*)(out + i) = o;
  }
}

// W (2048 x 2048, row-major K x N) -> Wt (N x K) fp16; 4 weights, one launch.
__global__ __launch_bounds__(256) void wtrans4(const float* __restrict__ W0, const float* __restrict__ W1,
                                               const float* __restrict__ W2, const float* __restrict__ W3,
                                               f16* __restrict__ Wt) {
  __shared__ float tile[32][33];
  int wi = blockIdx.y;
  const float* W = wi == 0 ? W0 : wi == 1 ? W1 : wi == 2 ? W2 : W3;
  f16* dst = Wt + (size_t)wi * D_ * D_;
  int bx = blockIdx.x & 63, by = blockIdx.x >> 6;
  int r0 = by << 5, c0 = bx << 5;
  int tx = threadIdx.x & 31, ty = threadIdx.x >> 5;
#pragma unroll
  for (int i = 0; i < 4; i++) {
    int r = ty + i * 8;
    tile[r][tx] = W[(size_t)(r0 + r) * D_ + c0 + tx];
  }
  __syncthreads();
#pragma unroll
  for (int i = 0; i < 4; i++) {
    int r = ty + i * 8;
    dst[(size_t)(c0 + r) * D_ + r0 + tx] = (f16)tile[tx][r];
  }
}

// swizzled LDS fragment read: [128][64] f16 half-tile, st_16x32 XOR swizzle.
DEV f16x8 lds_frag(const f16* half, int row, int s, int lg) {
  int byte = row * 128 + s * 64 + lg * 16;
  byte ^= (row & 4) << 3;  // ^32B when row bit2 set (st_16x32)
  return *(const f16x8*)((const char*)half + byte);
}

// C = A(MxK, row stride lda) * Bt(NxK)^T ; C row stride ldc. 256x256 tile,
// BK=64, 8 waves, 512 thr. m201-style schedule (R10 FUSION LESSON: N=6144
// fused QKV ran 823 TF vs ~1100 for N=2048 separate -- B=24MB streams the
// 4MB L2 4x per XCD; keep N=2048 launches, write into strided qkv via ldc).
template <typename CT>
__global__ __launch_bounds__(512, 2) void gemm8(const f16* __restrict__ A, const f16* __restrict__ Bt,
                                                CT* __restrict__ C, int M, int N, int K,
                                                int lda, int ldc) {
  __shared__ alignas(16) f16 As[2][2][128 * 64];
  __shared__ alignas(16) f16 Bs[2][2][128 * 64];
  int nbx = N >> 8;
  int nwg = (M >> 8) * nbx;  // must be %8==0 (our shapes: 256)
  int bid = blockIdx.x;
  int wg = (bid & 7) * (nwg >> 3) + (bid >> 3);  // XCD-contiguous chunks
  int bx = wg % nbx, by = wg / nbx;
  int tid = threadIdx.x, w = tid >> 6, l = tid & 63;
  int wm = w >> 2, wn = w & 3, lg = l >> 4, ln = l & 15;
  int nt = K >> 6;
  const f16* Ab = A + (size_t)(by * 256) * lda;
  const f16* Bb = Bt + (size_t)(bx * 256) * K;

  // stage one [128][64] half-tile: linear LDS dest, inverse-swizzled source.
  auto stageA = [&](const f16* src0, int kt, f16* dst) {
#pragma unroll
    for (int j = 0; j < 2; j++) {
      int c = j * 8 + w;                       // 1KB chunk
      int row = c * 8 + (l >> 3);
      int scol = ((l & 7) * 8) ^ ((row & 4) << 2);
      gl_lds16(src0 + (size_t)row * lda + kt * 64 + scol, (char*)dst + c * 1024);
    }
  };
  auto stageB = [&](const f16* src0, int kt, f16* dst) {
#pragma unroll
    for (int j = 0; j < 2; j++) {
      int c = j * 8 + w;                       // 1KB chunk
      int row = c * 8 + (l >> 3);
      int scol = ((l & 7) * 8) ^ ((row & 4) << 2);
      gl_lds16(src0 + (size_t)row * K + kt * 64 + scol, (char*)dst + c * 1024);
    }
  };

  f32x4 acc[8][4] = {};

  // prologue: tile0 A+B, tile1 B (A(t+1) staged at p0/p1, B(t+2) at p2/p3)
  stageA(Ab, 0, As[0][0]);
  stageA(Ab + (size_t)128 * lda, 0, As[0][1]);
  stageB(Bb, 0, Bs[0][0]);
  stageB(Bb + (size_t)128 * K, 0, Bs[0][1]);
  if (nt > 1) {
    stageB(Bb, 1, Bs[1][0]);
    stageB(Bb + (size_t)128 * K, 1, Bs[1][1]);
  }

  for (int t = 0; t < nt; t++) {
    // tile-entry drain: A(t)+B(t) landed for every wave, then collective barrier
    if (t + 2 < nt) asm volatile("s_waitcnt vmcnt(4)" ::: "memory");
    else            asm volatile("s_waitcnt vmcnt(0)" ::: "memory");
    __builtin_amdgcn_s_barrier();
    asm volatile("" ::: "memory");
    const f16* Ah = As[t & 1][wm];
    const f16* Bh = Bs[t & 1][wn >> 1];
    int br0 = (wn & 1) * 64;
    f16x8 a[4], b0[4], b1[4];
    // ---- p0: (mh0, k0); stage A(t+1) h0
#pragma unroll
    for (int i = 0; i < 4; i++) a[i] = lds_frag(Ah, i * 16 + ln, 0, lg);
#pragma unroll
    for (int i = 0; i < 4; i++) b0[i] = lds_frag(Bh, br0 + i * 16 + ln, 0, lg);
    if (t + 1 < nt) stageA(Ab, t + 1, As[(t + 1) & 1][0]);
    __builtin_amdgcn_s_barrier();
    asm volatile("" ::: "memory");
    __builtin_amdgcn_s_setprio(1);
#pragma unroll
    for (int mi = 0; mi < 4; mi++)
#pragma unroll
      for (int ni = 0; ni < 4; ni++)
        acc[mi][ni] = __builtin_amdgcn_mfma_f32_16x16x32_f16(a[mi], b0[ni], acc[mi][ni], 0, 0, 0);
    __builtin_amdgcn_s_setprio(0);
    __builtin_amdgcn_s_barrier();
    asm volatile("" ::: "memory");
    // ---- p1: (mh0, k1); stage A(t+1) h1
#pragma unroll
    for (int i = 0; i < 4; i++) a[i] = lds_frag(Ah, i * 16 + ln, 1, lg);
#pragma unroll
    for (int i = 0; i < 4; i++) b1[i] = lds_frag(Bh, br0 + i * 16 + ln, 1, lg);
    if (t + 1 < nt) stageA(Ab + (size_t)128 * lda, t + 1, As[(t + 1) & 1][1]);
    __builtin_amdgcn_s_barrier();
    asm volatile("" ::: "memory");
    __builtin_amdgcn_s_setprio(1);
#pragma unroll
    for (int mi = 0; mi < 4; mi++)
#pragma unroll
      for (int ni = 0; ni < 4; ni++)
        acc[mi][ni] = __builtin_amdgcn_mfma_f32_16x16x32_f16(a[mi], b1[ni], acc[mi][ni], 0, 0, 0);
    __builtin_amdgcn_s_setprio(0);
    __builtin_amdgcn_s_barrier();
    asm volatile("" ::: "memory");
    // ---- p2: (mh1, k0); B regs held; B LDS region free -> stage B(t+2) h0
#pragma unroll
    for (int i = 0; i < 4; i++) a[i] = lds_frag(Ah, 64 + i * 16 + ln, 0, lg);
    if (t + 2 < nt) stageB(Bb, t + 2, Bs[t & 1][0]);
    __builtin_amdgcn_s_barrier();
    asm volatile("" ::: "memory");
    __builtin_amdgcn_s_setprio(1);
#pragma unroll
    for (int mi = 0; mi < 4; mi++)
#pragma unroll
      for (int ni = 0; ni < 4; ni++)
        acc[mi + 4][ni] = __builtin_amdgcn_mfma_f32_16x16x32_f16(a[mi], b0[ni], acc[mi + 4][ni], 0, 0, 0);
    __builtin_amdgcn_s_setprio(0);
    __builtin_amdgcn_s_barrier();
    asm volatile("" ::: "memory");
    // ---- p3: (mh1, k1); stage B(t+2) h1
#pragma unroll
    for (int i = 0; i < 4; i++) a[i] = lds_frag(Ah, 64 + i * 16 + ln, 1, lg);
    if (t + 2 < nt) stageB(Bb + (size_t)128 * K, t + 2, Bs[t & 1][1]);
    __builtin_amdgcn_s_barrier();
    asm volatile("" ::: "memory");
    __builtin_amdgcn_s_setprio(1);
#pragma unroll
    for (int mi = 0; mi < 4; mi++)
#pragma unroll
      for (int ni = 0; ni < 4; ni++)
        acc[mi + 4][ni] = __builtin_amdgcn_mfma_f32_16x16x32_f16(a[mi], b1[ni], acc[mi + 4][ni], 0, 0, 0);
    __builtin_amdgcn_s_setprio(0);
    __builtin_amdgcn_s_barrier();
    asm volatile("" ::: "memory");
  }

  int row0 = by * 256 + wm * 128;
  int col0 = bx * 256 + wn * 64;
#pragma unroll
  for (int mi = 0; mi < 8; mi++)
#pragma unroll
    for (int ni = 0; ni < 4; ni++)
#pragma unroll
      for (int r4 = 0; r4 < 4; r4++) {
        int row = row0 + mi * 16 + lg * 4 + r4;
        int col = col0 + ni * 16 + ln;
        float o = acc[mi][ni][r4];
        if constexpr (sizeof(CT) == 2) {
          float oo = __shfl_xor(o, 1);
          if (!(ln & 1)) {
            f16x2 pp; pp[0] = (f16)o; pp[1] = (f16)oo;
            *(f16x2*)(&C[(size_t)row * ldc + col]) = pp;
          }
        } else {
          C[(size_t)row * ldc + col] = o;
        }
      }
}

__global__ __launch_bounds__(256) void rope_table(float2* __restrict__ tab, const int* __restrict__ st) {
  int i = blockIdx.x * 256 + threadIdx.x;  // S*64 entries
  int s = i >> 6, j = i & 63;
  float theta = powf(10000.f, -(float)j / 64.f);
  float ang = (float)(s + st[0]) * theta;
  tab[i] = make_float2(cosf(ang), sinf(ang));
}

// RoPE over the K columns (2048..4095) of the fused qkv buffer, in place.
__global__ __launch_bounds__(256) void rope_apply_k(f16* __restrict__ QKV, const float2* __restrict__ tab,
                                                    long npairs) {
  long i0 = (long)blockIdx.x * 256 + threadIdx.x;
  long stride = (long)gridDim.x * 256;
  for (long p = i0; p < npairs; p += stride) {
    long row = p >> 10;            // 1024 K-pairs per row
    int jp = (int)(p & 1023);
    int s = (int)(row & (S_ - 1));
    float2 cs = tab[s * 64 + (jp & 63)];
    f16* px = QKV + row * QKV_ST + 2048 + 2 * jp;
    f16x2 v = *(const f16x2*)px;
    float xe = (float)v[0], xo = (float)v[1];
    float re = xe * cs.x - xo * cs.y;
    float ro = xe * cs.y + xo * cs.x;
    f16x2 o; o[0] = (f16)re; o[1] = (f16)ro;
    *(f16x2*)px = o;
  }
}

// V (qkv cols 4096+) -> VT2 fragment-linear with the ZERO-SHUFFLE k<->kv
// mapping: per (bh, kv-tile t, nj, kk) one 1KB chunk; lane l=(lg*16+ln),
// element e owns V[d = nj*16 + ln][kv = t*64 + 16*(2kk+(e>>2)) + 4lg + (e&3)].
// Sigma matches QK^T's lane-local layout so attn's PV B-operand is a pure
// in-register pack. Both A (V) and B (P) use this sigma.
__global__ __launch_bounds__(256) void vtrans2(const f16* __restrict__ QKV, f16* __restrict__ VT2) {
  __shared__ alignas(16) f16 tile[64 * 128];  // [kv][d], 16B-chunk XOR-swizzled
  int t = blockIdx.x, bh = blockIdx.y, b = bh >> 4, h = bh & 15;
  int tid = threadIdx.x, w = tid >> 6, l = tid & 63, lg = l >> 4, ln = l & 15;
  const f16* src = QKV + (size_t)(b * S_ + t * 64) * QKV_ST + 4096 + h * HD_;
#pragma unroll
  for (int i = 0; i < 4; i++) {
    int idx = i * 256 + tid;            // 16B-unit index
    int r = idx >> 4, c8 = idx & 15;
    int c8s = c8 ^ ((r >> 3) & 3);      // swizzle: both sides use same XOR
    *(f16x8*)(&tile[r * 128 + c8s * 8]) = *(const f16x8*)(src + (size_t)r * QKV_ST + c8 * 8);
  }
  __syncthreads();
  f16* dst = VT2 + (size_t)(bh * 32 + t) * 16 * 512;
#pragma unroll
  for (int ci = 0; ci < 4; ci++) {
    int c = w * 4 + ci;                 // chunk = nj*2 + kk
    int nj = c >> 1, kk = c & 1;
    f16x8 v;
#pragma unroll
    for (int e = 0; e < 8; e++) {
      int r = 16 * (2 * kk + (e >> 2)) + 4 * lg + (e & 3);  // sigma(k-slot)
      int col = nj * 16 + ln;
      int c8s = (col >> 3) ^ ((r >> 3) & 3);
      v[e] = tile[r * 128 + c8s * 8 + (col & 7)];
    }
    *(f16x8*)(dst + (size_t)c * 512 + l * 8) = v;
  }
}

// flash attention, causal. 8 waves x 16 q-rows (QBLK=128), KV tile = 64,
// TWO KV-TILES PER BARRIER PERIOD: kls[2][2][64*128] (64KB, 2 blocks/CU).
// (R10: halving barrier visits took attn out of the top-5.) SWAPPED QK^T;
// lane-local softmax; ZERO-SHUFFLE PV (VT2 sigma); Q-RoPE fused into Q
// load; V chunks 0-7 after QK^T; UNIFORM blocks via causal pairing.
// Q/K read from fused qkv (stride 6144); O written back into Q columns.
// lsum quad-reduce deferred to epilogue. log2 scores; T13 defer-max THR=8.
__global__ __launch_bounds__(512, 4) void attn(f16* __restrict__ QKV, const f16* __restrict__ VT2,
                                               const float2* __restrict__ tab) {
  __shared__ alignas(16) f16 kls[2][2][64 * 128];
  int id = blockIdx.x;                   // 512 blocks
  int r8 = id & 7, j = id >> 3;          // j: 0..63 per XCD-residue
  int u = j & 7, g = j >> 3;             // u: pair id, g: bh group 0..7
  int bh = r8 + (g << 3);                // 8 bh's per XCD residue, bh-major
  int b = bh >> 4, h = bh & 15;
  int tid = threadIdx.x, w = tid >> 6, l = tid & 63, lg = l >> 4, ln = l & 15;

  const float QSCALE = 0.12751744910173355f;  // log2(e)/sqrt(128)
  const f16* kp = QKV + (size_t)(b * S_) * QKV_ST + 2048 + h * HD_;
  const f16* vp2 = VT2 + (size_t)bh * 32 * 16 * 512;

  auto stageK = [&](int buf, int half, int kv0) {
#pragma unroll
    for (int jj = 0; jj < 2; jj++) {
      int i = jj * 8 + w;
      int byte = i * 1024 + 16 * l;
      int r = byte >> 8;                       // row 0..63
      int c = (((byte >> 4) & 15) - r) & 15;   // inverse additive swizzle
      gl_lds16(kp + (size_t)(kv0 + r) * QKV_ST + c * 8, (char*)kls[buf][half] + i * 1024);
    }
  };

#pragma unroll 1
  for (int pi = 0; pi < 2; pi++) {
    int qsel = pi ? u : 15 - u;          // heavy pass first (K range in L2)
    int q0 = qsel << 7;
    int qrow = q0 + w * 16 + ln;         // this lane's q row (output column)
    f16* qp = QKV + (size_t)(b * S_ + qrow) * QKV_ST + h * HD_;
    const float2* tq = tab + (size_t)qrow * 64;
    f16x8 qf[4];
#pragma unroll
    for (int kc = 0; kc < 4; kc++) {
      f16x8 q = *(const f16x8*)(qp + kc * 32 + lg * 8);
#pragma unroll
      for (int p = 0; p < 4; p++) {
        float2 cs = tq[kc * 16 + lg * 4 + p];
        float e0 = (float)q[2 * p], e1 = (float)q[2 * p + 1];
        q[2 * p] = (f16)((e0 * cs.x - e1 * cs.y) * QSCALE);
        q[2 * p + 1] = (f16)((e0 * cs.y + e1 * cs.x) * QSCALE);
      }
      qf[kc] = q;
    }

    float m = -1e30f, lsum = 0.f;        // lsum: LANE-LOCAL partial
    f32x4 oacc[8] = {};                  // O^T[d = nj*16 + lg*4 + r4][q = ln]

    int np = qsel + 1;                   // periods; nt64 = 2*qsel+2 tiles
    int nt64 = 2 * qsel + 2;
    if (pi) __syncthreads();             // kls readers from prev pass done
    stageK(0, 0, 0);                     // prologue: period 0 (tiles 0,1)
    stageK(0, 1, 64);
#pragma unroll 1
    for (int p = 0; p < np; p++) {
      __syncthreads();  // drains period-p staging; all waves done with buf
      if (p + 1 < np) {
        stageK((p + 1) & 1, 0, (2 * p + 2) << 6);
        stageK((p + 1) & 1, 1, (2 * p + 3) << 6);
      }
#pragma unroll 1
      for (int ii = 0; ii < 2; ii++) {
        int t = 2 * p + ii;
        int kv0 = t << 6;
        // wave-uniform skip: this wave's rows all precede the tile
        if (kv0 > q0 + w * 16 + 15) continue;
        const f16* kb = kls[p & 1][ii];
        const f16* vt = vp2 + (size_t)t * 16 * 512;

        // S^T = K Q^T: sf[ni][r4] = S[kv = kv0 + ni*16 + lg*4 + r4][q = ln]
        f32x4 sf[4];
        __builtin_amdgcn_s_setprio(1);
#pragma unroll
        for (int ni = 0; ni < 4; ni++) {
          int n = ni * 16 + ln;
          f32x4 s = {0.f, 0.f, 0.f, 0.f};
#pragma unroll
          for (int kc = 0; kc < 4; kc++) {
            int mch = kc * 4 + lg;
            f16x8 kf = *(const f16x8*)(&kb[n * 128 + (((mch + n) & 15) << 3)]);
            s = __builtin_amdgcn_mfma_f32_16x16x32_f16(kf, qf[kc], s, 0, 0, 0);
          }
          sf[ni] = s;
        }
        __builtin_amdgcn_s_setprio(0);

        // V chunks 0-7 issued now; latency hides under mask+softmax
        f16x8 vfa[8];
#pragma unroll
        for (int c = 0; c < 8; c++) vfa[c] = *(const f16x8*)(vt + c * 512 + l * 8);

        if (t >= nt64 - 2) {  // only the two diagonal-adjacent tiles mask
#pragma unroll
          for (int ni = 0; ni < 4; ni++) {
            int kvg = kv0 + ni * 16 + lg * 4;
#pragma unroll
            for (int r4 = 0; r4 < 4; r4++)
              if (kvg + r4 > qrow) sf[ni][r4] = -1e30f;
          }
        }
        // online softmax (log2 domain), lane-local + 2 shfl (max only)
        float pm = fmaxf(fmaxf(fmaxf(sf[0][0], sf[0][1]), fmaxf(sf[0][2], sf[0][3])),
                         fmaxf(fmaxf(sf[1][0], sf[1][1]), fmaxf(sf[1][2], sf[1][3])));
        pm = fmaxf(pm, fmaxf(fmaxf(fmaxf(sf[2][0], sf[2][1]), fmaxf(sf[2][2], sf[2][3])),
                             fmaxf(fmaxf(sf[3][0], sf[3][1]), fmaxf(sf[3][2], sf[3][3]))));
        pm = fmaxf(pm, __shfl_xor(pm, 16));
        pm = fmaxf(pm, __shfl_xor(pm, 32));
        // T13 defer-max: keep old m while tile max hasn't outgrown it by >8
        float scl = 1.f;
        bool defer = __all(pm <= m + 8.f);
        if (!defer) {
          float mn = fmaxf(m, pm);
          scl = __builtin_amdgcn_exp2f(m - mn);
          m = mn;
        }
        float rsum = 0.f;
#pragma unroll
        for (int ni = 0; ni < 4; ni++)
#pragma unroll
          for (int r4 = 0; r4 < 4; r4++) {
            float pv = __builtin_amdgcn_exp2f(sf[ni][r4] - m);
            sf[ni][r4] = pv;
            rsum += pv;
          }
        lsum = lsum * scl + rsum;  // lane-local; cross-lane in epilogue

        // rescale O^T (skipped on defer tiles)
        if (!defer) {
#pragma unroll
          for (int nj = 0; nj < 8; nj++)
#pragma unroll
            for (int r4 = 0; r4 < 4; r4++) oacc[nj][r4] *= scl;
        }

        // ZERO-SHUFFLE pack: pa[kk] = [sf[2kk][0..3], sf[2kk+1][0..3]]
        f16x8 pa[2];
#pragma unroll
        for (int kk = 0; kk < 2; kk++) {
          i32x4 wv;
          wv.x = cvt_pk_i32(sf[2 * kk][0], sf[2 * kk][1]);
          wv.y = cvt_pk_i32(sf[2 * kk][2], sf[2 * kk][3]);
          wv.z = cvt_pk_i32(sf[2 * kk + 1][0], sf[2 * kk + 1][1]);
          wv.w = cvt_pk_i32(sf[2 * kk + 1][2], sf[2 * kk + 1][3]);
          pa[kk] = __builtin_bit_cast(f16x8, wv);
        }

        __builtin_amdgcn_s_setprio(1);
        // PV first half: nj 0-3 from pre-issued vfa (chunk = nj*2+kk)
#pragma unroll
        for (int kk = 0; kk < 2; kk++)
#pragma unroll
          for (int nj = 0; nj < 4; nj++)
            oacc[nj] = __builtin_amdgcn_mfma_f32_16x16x32_f16(vfa[nj * 2 + kk], pa[kk], oacc[nj], 0, 0, 0);
        // PV second half: nj 4-7, in-loop batches of 4
#pragma unroll
        for (int njb = 0; njb < 2; njb++) {
          f16x8 vf[4];
#pragma unroll
          for (int jj = 0; jj < 2; jj++)
#pragma unroll
            for (int kk = 0; kk < 2; kk++)
              vf[jj * 2 + kk] = *(const f16x8*)(vt + (size_t)(((4 + njb * 2 + jj) * 2 + kk) * 512) + l * 8);
#pragma unroll
          for (int kk = 0; kk < 2; kk++)
#pragma unroll
            for (int jj = 0; jj < 2; jj++)
              oacc[4 + njb * 2 + jj] = __builtin_amdgcn_mfma_f32_16x16x32_f16(
                  vf[jj * 2 + kk], pa[kk], oacc[4 + njb * 2 + jj], 0, 0, 0);
        }
        __builtin_amdgcn_s_setprio(0);
      }
    }

    // per-pass epilogue: quad-reduce lane-local lsum; write O into the Q
    // columns of qkv (this block's own rows, already consumed).
    lsum += __shfl_xor(lsum, 16);
    lsum += __shfl_xor(lsum, 32);
    float inv = 1.f / lsum;
#pragma unroll
    for (int nj = 0; nj < 8; nj++) {
      f16x4v ov;
#pragma unroll
      for (int r4 = 0; r4 < 4; r4++) ov[r4] = (f16)(oacc[nj][r4] * inv);
      *(f16x4v*)(qp + nj * 16 + lg * 4) = ov;
    }
  }
}

extern "C" void kernel_launch(void* const* d_in, const int* in_sizes, int n_in,
                              void* d_out, int out_size, void* d_ws, size_t ws_size,
                              hipStream_t stream) {
  (void)in_sizes; (void)n_in; (void)out_size; (void)ws_size;
  const float* x = (const float*)d_in[0];
  // d_in[1] = mask (causal, reproduced analytically)
  const float* Wq = (const float*)d_in[2];
  const float* Wk = (const float*)d_in[3];
  const float* Wv = (const float*)d_in[4];
  const float* Wo = (const float*)d_in[5];
  const int* stp = (const int*)d_in[6];
  float* out = (float*)d_out;

  const size_t MS = (size_t)B_ * S_;  // 8192
  f16* xh = (f16*)d_ws;                         // 32MB
  f16* wqt = xh + MS * D_;                      // wqt|wkt|wvt|wot contiguous, 32MB
  f16* wkt = wqt + (size_t)D_ * D_;
  f16* wvt = wkt + (size_t)D_ * D_;
  f16* wot = wvt + (size_t)D_ * D_;
  f16* qkv = wot + (size_t)D_ * D_;             // 8192 x 6144 f16, ~100MB
  float2* tab = (float2*)(qkv + MS * (size_t)QKV_ST);
  f16* vt2 = xh;  // reuse: x consumed after the QKV GEMMs

  cvt_f32_to_f16<<<16384, 256, 0, stream>>>(x, xh, (long)(MS * D_));
  wtrans4<<<dim3(4096, 4), 256, 0, stream>>>(Wq, Wk, Wv, Wo, wqt);
  // 3 separate N=2048 GEMMs (R10: fused N=6144 was 823 TF vs ~1100 here),
  // writing into the strided qkv buffer (ldc=6144) to keep the fused layout.
  gemm8<f16><<<256, 512, 0, stream>>>(xh, wqt, qkv, 8192, 2048, 2048, 2048, QKV_ST);
  gemm8<f16><<<256, 512, 0, stream>>>(xh, wkt, qkv + 2048, 8192, 2048, 2048, 2048, QKV_ST);
  gemm8<f16><<<256, 512, 0, stream>>>(xh, wvt, qkv + 4096, 8192, 2048, 2048, 2048, QKV_ST);
  rope_table<<<512, 256, 0, stream>>>(tab, stp);
  // K roped in place (qkv cols 2048-4095); Q-RoPE fused into attn.
  rope_apply_k<<<4096, 256, 0, stream>>>(qkv, tab, (long)(MS * 1024));
  vtrans2<<<dim3(32, 64), 256, 0, stream>>>(qkv, vt2);
  // attn reads Q/K from qkv, writes O into qkv's Q columns
  attn<<<512, 512, 0, stream>>>(qkv, vt2, tab);
  // Wo GEMM: A = qkv Q-columns (lda=6144)
  gemm8<float><<<256, 512, 0, stream>>>(qkv, wot, out, 8192, 2048, 2048, QKV_ST, 2048);
}

// Round 12
// 457.942 us; speedup vs baseline: 1.0242x; 1.0242x over previous
//
#include <hip/hip_runtime.h>
#include <hip/hip_fp16.h>

typedef _Float16 f16;
typedef __attribute__((ext_vector_type(2))) _Float16 f16x2;
typedef __attribute__((ext_vector_type(4))) _Float16 f16x4v;
typedef __attribute__((ext_vector_type(8))) _Float16 f16x8;
typedef __attribute__((ext_vector_type(4))) float f32x4;
typedef __attribute__((ext_vector_type(4))) int i32x4;

#define DEV __device__ __forceinline__

static constexpr int S_ = 2048;
static constexpr int D_ = 2048;
static constexpr int H_ = 16;
static constexpr int HD_ = 128;
static constexpr int B_ = 4;
static constexpr int QKV_ST = 6144;  // fused qkv row stride (Q|K|V)

typedef const __attribute__((address_space(1))) void* gptr_t;
typedef __attribute__((address_space(3))) void* lptr_t;

// async global->LDS, 16B per lane. LDS dest must be wave-uniform; HW writes
// dest + lane*16 (m104 semantics). Compiler manages m0.
DEV void gl_lds16(const void* gsrc, void* lds) {
  __builtin_amdgcn_global_load_lds((gptr_t)gsrc, (lptr_t)lds, 16, 0, 0);
}

// f32 pair -> packed f16x2 bits (v_cvt_pkrtz_f16_f32)
DEV int cvt_pk_i32(float a, float b) {
  return __builtin_bit_cast(int, __builtin_amdgcn_cvt_pkrtz(a, b));
}

__global__ __launch_bounds__(256) void cvt_f32_to_f16(const float* __restrict__ in,
                                                      f16* __restrict__ out, long n) {
  long i0 = ((long)blockIdx.x * 256 + threadIdx.x) * 4;
  long stride = (long)gridDim.x * 256 * 4;
  for (long i = i0; i < n; i += stride) {
    float4 v = *(const float4*)(in + i);
    f16x4v o;
    o[0] = (f16)v.x; o[1] = (f16)v.y; o[2] = (f16)v.z; o[3] = (f16)v.w;
    *(f16x4v*)(out + i) = o;
  }
}

// W (2048 x 2048, row-major K x N) -> Wt (N x K) fp16; 4 weights, one launch.
__global__ __launch_bounds__(256) void wtrans4(const float* __restrict__ W0, const float* __restrict__ W1,
                                               const float* __restrict__ W2, const float* __restrict__ W3,
                                               f16* __restrict__ Wt) {
  __shared__ float tile[32][33];
  int wi = blockIdx.y;
  const float* W = wi == 0 ? W0 : wi == 1 ? W1 : wi == 2 ? W2 : W3;
  f16* dst = Wt + (size_t)wi * D_ * D_;
  int bx = blockIdx.x & 63, by = blockIdx.x >> 6;
  int r0 = by << 5, c0 = bx << 5;
  int tx = threadIdx.x & 31, ty = threadIdx.x >> 5;
#pragma unroll
  for (int i = 0; i < 4; i++) {
    int r = ty + i * 8;
    tile[r][tx] = W[(size_t)(r0 + r) * D_ + c0 + tx];
  }
  __syncthreads();
#pragma unroll
  for (int i = 0; i < 4; i++) {
    int r = ty + i * 8;
    dst[(size_t)(c0 + r) * D_ + r0 + tx] = (f16)tile[tx][r];
  }
}

// swizzled LDS fragment read: [128][64] f16 half-tile, st_16x32 XOR swizzle.
DEV f16x8 lds_frag(const f16* half, int row, int s, int lg) {
  int byte = row * 128 + s * 64 + lg * 16;
  byte ^= (row & 4) << 3;  // ^32B when row bit2 set (st_16x32)
  return *(const f16x8*)((const char*)half + byte);
}

// C = A(MxK, row stride lda) * Bt(NxK)^T ; C row stride ldc. 256x256 tile,
// BK=64, 8 waves, 512 thr. m201-style schedule (R10 FUSION LESSON: N=6144
// fused QKV ran 823 TF vs ~1100 for N=2048 separate -- B=24MB streams the
// 4MB L2 4x per XCD; keep N=2048 launches, write into strided qkv via ldc).
template <typename CT>
__global__ __launch_bounds__(512, 2) void gemm8(const f16* __restrict__ A, const f16* __restrict__ Bt,
                                                CT* __restrict__ C, int M, int N, int K,
                                                int lda, int ldc) {
  __shared__ alignas(16) f16 As[2][2][128 * 64];
  __shared__ alignas(16) f16 Bs[2][2][128 * 64];
  int nbx = N >> 8;
  int nwg = (M >> 8) * nbx;  // must be %8==0 (our shapes: 256)
  int bid = blockIdx.x;
  int wg = (bid & 7) * (nwg >> 3) + (bid >> 3);  // XCD-contiguous chunks
  int bx = wg % nbx, by = wg / nbx;
  int tid = threadIdx.x, w = tid >> 6, l = tid & 63;
  int wm = w >> 2, wn = w & 3, lg = l >> 4, ln = l & 15;
  int nt = K >> 6;
  const f16* Ab = A + (size_t)(by * 256) * lda;
  const f16* Bb = Bt + (size_t)(bx * 256) * K;

  // stage one [128][64] half-tile: linear LDS dest, inverse-swizzled source.
  auto stageA = [&](const f16* src0, int kt, f16* dst) {
#pragma unroll
    for (int j = 0; j < 2; j++) {
      int c = j * 8 + w;                       // 1KB chunk
      int row = c * 8 + (l >> 3);
      int scol = ((l & 7) * 8) ^ ((row & 4) << 2);
      gl_lds16(src0 + (size_t)row * lda + kt * 64 + scol, (char*)dst + c * 1024);
    }
  };
  auto stageB = [&](const f16* src0, int kt, f16* dst) {
#pragma unroll
    for (int j = 0; j < 2; j++) {
      int c = j * 8 + w;                       // 1KB chunk
      int row = c * 8 + (l >> 3);
      int scol = ((l & 7) * 8) ^ ((row & 4) << 2);
      gl_lds16(src0 + (size_t)row * K + kt * 64 + scol, (char*)dst + c * 1024);
    }
  };

  f32x4 acc[8][4] = {};

  // prologue: tile0 A+B, tile1 B (A(t+1) staged at p0/p1, B(t+2) at p2/p3)
  stageA(Ab, 0, As[0][0]);
  stageA(Ab + (size_t)128 * lda, 0, As[0][1]);
  stageB(Bb, 0, Bs[0][0]);
  stageB(Bb + (size_t)128 * K, 0, Bs[0][1]);
  if (nt > 1) {
    stageB(Bb, 1, Bs[1][0]);
    stageB(Bb + (size_t)128 * K, 1, Bs[1][1]);
  }

  for (int t = 0; t < nt; t++) {
    // tile-entry drain: A(t)+B(t) landed for every wave, then collective barrier
    if (t + 2 < nt) asm volatile("s_waitcnt vmcnt(4)" ::: "memory");
    else            asm volatile("s_waitcnt vmcnt(0)" ::: "memory");
    __builtin_amdgcn_s_barrier();
    asm volatile("" ::: "memory");
    const f16* Ah = As[t & 1][wm];
    const f16* Bh = Bs[t & 1][wn >> 1];
    int br0 = (wn & 1) * 64;
    f16x8 a[4], b0[4], b1[4];
    // ---- p0: (mh0, k0); stage A(t+1) h0
#pragma unroll
    for (int i = 0; i < 4; i++) a[i] = lds_frag(Ah, i * 16 + ln, 0, lg);
#pragma unroll
    for (int i = 0; i < 4; i++) b0[i] = lds_frag(Bh, br0 + i * 16 + ln, 0, lg);
    if (t + 1 < nt) stageA(Ab, t + 1, As[(t + 1) & 1][0]);
    __builtin_amdgcn_s_barrier();
    asm volatile("" ::: "memory");
    __builtin_amdgcn_s_setprio(1);
#pragma unroll
    for (int mi = 0; mi < 4; mi++)
#pragma unroll
      for (int ni = 0; ni < 4; ni++)
        acc[mi][ni] = __builtin_amdgcn_mfma_f32_16x16x32_f16(a[mi], b0[ni], acc[mi][ni], 0, 0, 0);
    __builtin_amdgcn_s_setprio(0);
    __builtin_amdgcn_s_barrier();
    asm volatile("" ::: "memory");
    // ---- p1: (mh0, k1); stage A(t+1) h1
#pragma unroll
    for (int i = 0; i < 4; i++) a[i] = lds_frag(Ah, i * 16 + ln, 1, lg);
#pragma unroll
    for (int i = 0; i < 4; i++) b1[i] = lds_frag(Bh, br0 + i * 16 + ln, 1, lg);
    if (t + 1 < nt) stageA(Ab + (size_t)128 * lda, t + 1, As[(t + 1) & 1][1]);
    __builtin_amdgcn_s_barrier();
    asm volatile("" ::: "memory");
    __builtin_amdgcn_s_setprio(1);
#pragma unroll
    for (int mi = 0; mi < 4; mi++)
#pragma unroll
      for (int ni = 0; ni < 4; ni++)
        acc[mi][ni] = __builtin_amdgcn_mfma_f32_16x16x32_f16(a[mi], b1[ni], acc[mi][ni], 0, 0, 0);
    __builtin_amdgcn_s_setprio(0);
    __builtin_amdgcn_s_barrier();
    asm volatile("" ::: "memory");
    // ---- p2: (mh1, k0); B regs held; B LDS region free -> stage B(t+2) h0
#pragma unroll
    for (int i = 0; i < 4; i++) a[i] = lds_frag(Ah, 64 + i * 16 + ln, 0, lg);
    if (t + 2 < nt) stageB(Bb, t + 2, Bs[t & 1][0]);
    __builtin_amdgcn_s_barrier();
    asm volatile("" ::: "memory");
    __builtin_amdgcn_s_setprio(1);
#pragma unroll
    for (int mi = 0; mi < 4; mi++)
#pragma unroll
      for (int ni = 0; ni < 4; ni++)
        acc[mi + 4][ni] = __builtin_amdgcn_mfma_f32_16x16x32_f16(a[mi], b0[ni], acc[mi + 4][ni], 0, 0, 0);
    __builtin_amdgcn_s_setprio(0);
    __builtin_amdgcn_s_barrier();
    asm volatile("" ::: "memory");
    // ---- p3: (mh1, k1); stage B(t+2) h1
#pragma unroll
    for (int i = 0; i < 4; i++) a[i] = lds_frag(Ah, 64 + i * 16 + ln, 1, lg);
    if (t + 2 < nt) stageB(Bb + (size_t)128 * K, t + 2, Bs[t & 1][1]);
    __builtin_amdgcn_s_barrier();
    asm volatile("" ::: "memory");
    __builtin_amdgcn_s_setprio(1);
#pragma unroll
    for (int mi = 0; mi < 4; mi++)
#pragma unroll
      for (int ni = 0; ni < 4; ni++)
        acc[mi + 4][ni] = __builtin_amdgcn_mfma_f32_16x16x32_f16(a[mi], b1[ni], acc[mi + 4][ni], 0, 0, 0);
    __builtin_amdgcn_s_setprio(0);
    __builtin_amdgcn_s_barrier();
    asm volatile("" ::: "memory");
  }

  int row0 = by * 256 + wm * 128;
  int col0 = bx * 256 + wn * 64;
#pragma unroll
  for (int mi = 0; mi < 8; mi++)
#pragma unroll
    for (int ni = 0; ni < 4; ni++)
#pragma unroll
      for (int r4 = 0; r4 < 4; r4++) {
        int row = row0 + mi * 16 + lg * 4 + r4;
        int col = col0 + ni * 16 + ln;
        float o = acc[mi][ni][r4];
        if constexpr (sizeof(CT) == 2) {
          float oo = __shfl_xor(o, 1);
          if (!(ln & 1)) {
            f16x2 pp; pp[0] = (f16)o; pp[1] = (f16)oo;
            *(f16x2*)(&C[(size_t)row * ldc + col]) = pp;
          }
        } else {
          C[(size_t)row * ldc + col] = o;
        }
      }
}

__global__ __launch_bounds__(256) void rope_table(float2* __restrict__ tab, const int* __restrict__ st) {
  int i = blockIdx.x * 256 + threadIdx.x;  // S*64 entries
  int s = i >> 6, j = i & 63;
  float theta = powf(10000.f, -(float)j / 64.f);
  float ang = (float)(s + st[0]) * theta;
  tab[i] = make_float2(cosf(ang), sinf(ang));
}

// RoPE over the K columns (2048..4095) of the fused qkv buffer, in place.
__global__ __launch_bounds__(256) void rope_apply_k(f16* __restrict__ QKV, const float2* __restrict__ tab,
                                                    long npairs) {
  long i0 = (long)blockIdx.x * 256 + threadIdx.x;
  long stride = (long)gridDim.x * 256;
  for (long p = i0; p < npairs; p += stride) {
    long row = p >> 10;            // 1024 K-pairs per row
    int jp = (int)(p & 1023);
    int s = (int)(row & (S_ - 1));
    float2 cs = tab[s * 64 + (jp & 63)];
    f16* px = QKV + row * QKV_ST + 2048 + 2 * jp;
    f16x2 v = *(const f16x2*)px;
    float xe = (float)v[0], xo = (float)v[1];
    float re = xe * cs.x - xo * cs.y;
    float ro = xe * cs.y + xo * cs.x;
    f16x2 o; o[0] = (f16)re; o[1] = (f16)ro;
    *(f16x2*)px = o;
  }
}

// V (qkv cols 4096+) -> VT2 fragment-linear with the ZERO-SHUFFLE k<->kv
// mapping: per (bh, kv-tile t, nj, kk) one 1KB chunk; lane l=(lg*16+ln),
// element e owns V[d = nj*16 + ln][kv = t*64 + 16*(2kk+(e>>2)) + 4lg + (e&3)].
// Sigma matches QK^T's lane-local layout so attn's PV B-operand is a pure
// in-register pack. Both A (V) and B (P) use this sigma.
__global__ __launch_bounds__(256) void vtrans2(const f16* __restrict__ QKV, f16* __restrict__ VT2) {
  __shared__ alignas(16) f16 tile[64 * 128];  // [kv][d], 16B-chunk XOR-swizzled
  int t = blockIdx.x, bh = blockIdx.y, b = bh >> 4, h = bh & 15;
  int tid = threadIdx.x, w = tid >> 6, l = tid & 63, lg = l >> 4, ln = l & 15;
  const f16* src = QKV + (size_t)(b * S_ + t * 64) * QKV_ST + 4096 + h * HD_;
#pragma unroll
  for (int i = 0; i < 4; i++) {
    int idx = i * 256 + tid;            // 16B-unit index
    int r = idx >> 4, c8 = idx & 15;
    int c8s = c8 ^ ((r >> 3) & 3);      // swizzle: both sides use same XOR
    *(f16x8*)(&tile[r * 128 + c8s * 8]) = *(const f16x8*)(src + (size_t)r * QKV_ST + c8 * 8);
  }
  __syncthreads();
  f16* dst = VT2 + (size_t)(bh * 32 + t) * 16 * 512;
#pragma unroll
  for (int ci = 0; ci < 4; ci++) {
    int c = w * 4 + ci;                 // chunk = nj*2 + kk
    int nj = c >> 1, kk = c & 1;
    f16x8 v;
#pragma unroll
    for (int e = 0; e < 8; e++) {
      int r = 16 * (2 * kk + (e >> 2)) + 4 * lg + (e & 3);  // sigma(k-slot)
      int col = nj * 16 + ln;
      int c8s = (col >> 3) ^ ((r >> 3) & 3);
      v[e] = tile[r * 128 + c8s * 8 + (col & 7)];
    }
    *(f16x8*)(dst + (size_t)c * 512 + l * 8) = v;
  }
}

// flash attention, causal. 8 waves x 32 q-rows (QBLK=256), KV tile = 64.
// HEAVY WAVES (m214 thesis): each wave owns TWO 16-row q-groups (A: ln,
// B: ln+16). Every shared operand amortizes 2x -- each K LDS fragment
// feeds QK MFMAs for A and B; each V global fragment feeds PV for A and
// B; staging/barrier/loop overhead unchanged per tile but serves 64 MFMA
// instead of 32. (R7-R11: attn stuck at ~127us, MfmaUtil 24%, VGPR only
// 64 -- TLP rearrangements (R8/R9) were null; m214 hit ~900 TF at ~25%
// occupancy with 205-VGPR waves => go ILP.) 256 blocks (64bh x 4 paired
// q-tiles (7-u, u)), 1/CU, uniform 36 kv-tiles/block. 2-tile barrier
// periods (kls[2][2], 64KB); pass tile counts 4q+4 are even.
// SWAPPED QK^T; lane-local softmax; ZERO-SHUFFLE PV (VT2 sigma); Q-RoPE
// fused into Q load; Q/K from fused qkv (stride 6144); O into Q columns.
// lsum quad-reduce deferred to epilogue. log2 scores; T13 defer-max THR=8.
__global__ __launch_bounds__(512, 2) void attn(f16* __restrict__ QKV, const f16* __restrict__ VT2,
                                               const float2* __restrict__ tab) {
  __shared__ alignas(16) f16 kls[2][2][64 * 128];
  int id = blockIdx.x;                   // 256 blocks
  int r8 = id & 7, j = id >> 3;          // j: 0..31 per XCD-residue
  int u = j & 3, g = j >> 2;             // u: pair id, g: bh group 0..7
  int bh = r8 + (g << 3);                // 8 bh's per XCD residue, bh-major
  int b = bh >> 4, h = bh & 15;
  int tid = threadIdx.x, w = tid >> 6, l = tid & 63, lg = l >> 4, ln = l & 15;

  const float QSCALE = 0.12751744910173355f;  // log2(e)/sqrt(128)
  const f16* kp = QKV + (size_t)(b * S_) * QKV_ST + 2048 + h * HD_;
  const f16* vp2 = VT2 + (size_t)bh * 32 * 16 * 512;

  auto stageK = [&](int buf, int half, int kv0) {
#pragma unroll
    for (int jj = 0; jj < 2; jj++) {
      int i = jj * 8 + w;
      int byte = i * 1024 + 16 * l;
      int r = byte >> 8;                       // row 0..63
      int c = (((byte >> 4) & 15) - r) & 15;   // inverse additive swizzle
      gl_lds16(kp + (size_t)(kv0 + r) * QKV_ST + c * 8, (char*)kls[buf][half] + i * 1024);
    }
  };

#pragma unroll 1
  for (int pi = 0; pi < 2; pi++) {
    int qsel = pi ? u : 7 - u;           // heavy pass first (K range in L2)
    int q0 = qsel << 8;                  // 256-row q-tile
    int qrA = q0 + w * 32 + ln;          // group A q row
    int qrB = qrA + 16;                  // group B q row
    f16* qpA = QKV + (size_t)(b * S_ + qrA) * QKV_ST + h * HD_;
    f16* qpB = QKV + (size_t)(b * S_ + qrB) * QKV_ST + h * HD_;
    f16x8 qfA[4], qfB[4];
#pragma unroll
    for (int grp = 0; grp < 2; grp++) {
      f16* qp = grp ? qpB : qpA;
      const float2* tq = tab + (size_t)(grp ? qrB : qrA) * 64;
#pragma unroll
      for (int kc = 0; kc < 4; kc++) {
        f16x8 q = *(const f16x8*)(qp + kc * 32 + lg * 8);
#pragma unroll
        for (int p = 0; p < 4; p++) {
          float2 cs = tq[kc * 16 + lg * 4 + p];
          float e0 = (float)q[2 * p], e1 = (float)q[2 * p + 1];
          q[2 * p] = (f16)((e0 * cs.x - e1 * cs.y) * QSCALE);
          q[2 * p + 1] = (f16)((e0 * cs.y + e1 * cs.x) * QSCALE);
        }
        if (grp) qfB[kc] = q; else qfA[kc] = q;
      }
    }

    float mA = -1e30f, lsA = 0.f, mB = -1e30f, lsB = 0.f;  // lane-local
    f32x4 oaccA[8] = {}, oaccB[8] = {};  // O^T[d = nj*16 + lg*4 + r4][q]

    int nt = 4 * qsel + 4;               // tiles (even); np periods
    int np = nt >> 1;
    int twave = (q0 + w * 32 + 31) >> 6; // this wave's diagonal tile
    if (pi) __syncthreads();             // kls readers from prev pass done
    stageK(0, 0, 0);                     // prologue: period 0 (tiles 0,1)
    stageK(0, 1, 64);
#pragma unroll 1
    for (int p = 0; p < np; p++) {
      __syncthreads();  // drains period-p staging; all waves done with buf
      if (p + 1 < np) {
        stageK((p + 1) & 1, 0, (2 * p + 2) << 6);
        stageK((p + 1) & 1, 1, (2 * p + 3) << 6);
      }
#pragma unroll 1
      for (int ii = 0; ii < 2; ii++) {
        int t = 2 * p + ii;
        int kv0 = t << 6;
        // wave-uniform skip: all 32 of this wave's rows precede the tile
        if (t > twave) continue;
        const f16* kb = kls[p & 1][ii];
        const f16* vt = vp2 + (size_t)t * 16 * 512;

        // S^T = K Q^T for BOTH groups; each kf fragment feeds 2 MFMAs.
        f32x4 sfA[4], sfB[4];
        __builtin_amdgcn_s_setprio(1);
#pragma unroll
        for (int ni = 0; ni < 4; ni++) {
          int n = ni * 16 + ln;
          f32x4 sA = {0.f, 0.f, 0.f, 0.f};
          f32x4 sB = {0.f, 0.f, 0.f, 0.f};
#pragma unroll
          for (int kc = 0; kc < 4; kc++) {
            int mch = kc * 4 + lg;
            f16x8 kf = *(const f16x8*)(&kb[n * 128 + (((mch + n) & 15) << 3)]);
            sA = __builtin_amdgcn_mfma_f32_16x16x32_f16(kf, qfA[kc], sA, 0, 0, 0);
            sB = __builtin_amdgcn_mfma_f32_16x16x32_f16(kf, qfB[kc], sB, 0, 0, 0);
          }
          sfA[ni] = sA; sfB[ni] = sB;
        }
        __builtin_amdgcn_s_setprio(0);

        // V chunks 0-7 issued now; latency hides under mask+softmax
        f16x8 vfa[8];
#pragma unroll
        for (int c = 0; c < 8; c++) vfa[c] = *(const f16x8*)(vt + c * 512 + l * 8);

        if (t == twave) {  // wave's diagonal tile: mask both groups
#pragma unroll
          for (int ni = 0; ni < 4; ni++) {
            int kvg = kv0 + ni * 16 + lg * 4;
#pragma unroll
            for (int r4 = 0; r4 < 4; r4++) {
              if (kvg + r4 > qrA) sfA[ni][r4] = -1e30f;
              if (kvg + r4 > qrB) sfB[ni][r4] = -1e30f;
            }
          }
        }
        // online softmax (log2 domain) -- group A, then group B
        f16x8 pa[2], pb[2];
        {
          float pm = fmaxf(fmaxf(fmaxf(sfA[0][0], sfA[0][1]), fmaxf(sfA[0][2], sfA[0][3])),
                           fmaxf(fmaxf(sfA[1][0], sfA[1][1]), fmaxf(sfA[1][2], sfA[1][3])));
          pm = fmaxf(pm, fmaxf(fmaxf(fmaxf(sfA[2][0], sfA[2][1]), fmaxf(sfA[2][2], sfA[2][3])),
                               fmaxf(fmaxf(sfA[3][0], sfA[3][1]), fmaxf(sfA[3][2], sfA[3][3]))));
          pm = fmaxf(pm, __shfl_xor(pm, 16));
          pm = fmaxf(pm, __shfl_xor(pm, 32));
          float scl = 1.f;
          bool defer = __all(pm <= mA + 8.f);
          if (!defer) {
            float mn = fmaxf(mA, pm);
            scl = __builtin_amdgcn_exp2f(mA - mn);
            mA = mn;
          }
          float rsum = 0.f;
#pragma unroll
          for (int ni = 0; ni < 4; ni++)
#pragma unroll
            for (int r4 = 0; r4 < 4; r4++) {
              float pv = __builtin_amdgcn_exp2f(sfA[ni][r4] - mA);
              sfA[ni][r4] = pv;
              rsum += pv;
            }
          lsA = lsA * scl + rsum;
          if (!defer) {
#pragma unroll
            for (int nj = 0; nj < 8; nj++)
#pragma unroll
              for (int r4 = 0; r4 < 4; r4++) oaccA[nj][r4] *= scl;
          }
#pragma unroll
          for (int kk = 0; kk < 2; kk++) {
            i32x4 wv;
            wv.x = cvt_pk_i32(sfA[2 * kk][0], sfA[2 * kk][1]);
            wv.y = cvt_pk_i32(sfA[2 * kk][2], sfA[2 * kk][3]);
            wv.z = cvt_pk_i32(sfA[2 * kk + 1][0], sfA[2 * kk + 1][1]);
            wv.w = cvt_pk_i32(sfA[2 * kk + 1][2], sfA[2 * kk + 1][3]);
            pa[kk] = __builtin_bit_cast(f16x8, wv);
          }
        }
        {
          float pm = fmaxf(fmaxf(fmaxf(sfB[0][0], sfB[0][1]), fmaxf(sfB[0][2], sfB[0][3])),
                           fmaxf(fmaxf(sfB[1][0], sfB[1][1]), fmaxf(sfB[1][2], sfB[1][3])));
          pm = fmaxf(pm, fmaxf(fmaxf(fmaxf(sfB[2][0], sfB[2][1]), fmaxf(sfB[2][2], sfB[2][3])),
                               fmaxf(fmaxf(sfB[3][0], sfB[3][1]), fmaxf(sfB[3][2], sfB[3][3]))));
          pm = fmaxf(pm, __shfl_xor(pm, 16));
          pm = fmaxf(pm, __shfl_xor(pm, 32));
          float scl = 1.f;
          bool defer = __all(pm <= mB + 8.f);
          if (!defer) {
            float mn = fmaxf(mB, pm);
            scl = __builtin_amdgcn_exp2f(mB - mn);
            mB = mn;
          }
          float rsum = 0.f;
#pragma unroll
          for (int ni = 0; ni < 4; ni++)
#pragma unroll
            for (int r4 = 0; r4 < 4; r4++) {
              float pv = __builtin_amdgcn_exp2f(sfB[ni][r4] - mB);
              sfB[ni][r4] = pv;
              rsum += pv;
            }
          lsB = lsB * scl + rsum;
          if (!defer) {
#pragma unroll
            for (int nj = 0; nj < 8; nj++)
#pragma unroll
              for (int r4 = 0; r4 < 4; r4++) oaccB[nj][r4] *= scl;
          }
#pragma unroll
          for (int kk = 0; kk < 2; kk++) {
            i32x4 wv;
            wv.x = cvt_pk_i32(sfB[2 * kk][0], sfB[2 * kk][1]);
            wv.y = cvt_pk_i32(sfB[2 * kk][2], sfB[2 * kk][3]);
            wv.z = cvt_pk_i32(sfB[2 * kk + 1][0], sfB[2 * kk + 1][1]);
            wv.w = cvt_pk_i32(sfB[2 * kk + 1][2], sfB[2 * kk + 1][3]);
            pb[kk] = __builtin_bit_cast(f16x8, wv);
          }
        }

        __builtin_amdgcn_s_setprio(1);
        // PV first half: nj 0-3; each vfa fragment feeds A and B
#pragma unroll
        for (int kk = 0; kk < 2; kk++)
#pragma unroll
          for (int nj = 0; nj < 4; nj++) {
            oaccA[nj] = __builtin_amdgcn_mfma_f32_16x16x32_f16(vfa[nj * 2 + kk], pa[kk], oaccA[nj], 0, 0, 0);
            oaccB[nj] = __builtin_amdgcn_mfma_f32_16x16x32_f16(vfa[nj * 2 + kk], pb[kk], oaccB[nj], 0, 0, 0);
          }
        // PV second half: nj 4-7, batches of 4 fragments, both groups
#pragma unroll
        for (int njb = 0; njb < 2; njb++) {
          f16x8 vf[4];
#pragma unroll
          for (int jj = 0; jj < 2; jj++)
#pragma unroll
            for (int kk = 0; kk < 2; kk++)
              vf[jj * 2 + kk] = *(const f16x8*)(vt + (size_t)(((4 + njb * 2 + jj) * 2 + kk) * 512) + l * 8);
#pragma unroll
          for (int kk = 0; kk < 2; kk++)
#pragma unroll
            for (int jj = 0; jj < 2; jj++) {
              int nj = 4 + njb * 2 + jj;
              oaccA[nj] = __builtin_amdgcn_mfma_f32_16x16x32_f16(vf[jj * 2 + kk], pa[kk], oaccA[nj], 0, 0, 0);
              oaccB[nj] = __builtin_amdgcn_mfma_f32_16x16x32_f16(vf[jj * 2 + kk], pb[kk], oaccB[nj], 0, 0, 0);
            }
        }
        __builtin_amdgcn_s_setprio(0);
      }
    }

    // per-pass epilogue: quad-reduce lane-local lsum; write O for both
    // groups into the Q columns of qkv (own rows, already consumed).
    lsA += __shfl_xor(lsA, 16);
    lsA += __shfl_xor(lsA, 32);
    lsB += __shfl_xor(lsB, 16);
    lsB += __shfl_xor(lsB, 32);
    float invA = 1.f / lsA, invB = 1.f / lsB;
#pragma unroll
    for (int nj = 0; nj < 8; nj++) {
      f16x4v ovA, ovB;
#pragma unroll
      for (int r4 = 0; r4 < 4; r4++) {
        ovA[r4] = (f16)(oaccA[nj][r4] * invA);
        ovB[r4] = (f16)(oaccB[nj][r4] * invB);
      }
      *(f16x4v*)(qpA + nj * 16 + lg * 4) = ovA;
      *(f16x4v*)(qpB + nj * 16 + lg * 4) = ovB;
    }
  }
}

extern "C" void kernel_launch(void* const* d_in, const int* in_sizes, int n_in,
                              void* d_out, int out_size, void* d_ws, size_t ws_size,
                              hipStream_t stream) {
  (void)in_sizes; (void)n_in; (void)out_size; (void)ws_size;
  const float* x = (const float*)d_in[0];
  // d_in[1] = mask (causal, reproduced analytically)
  const float* Wq = (const float*)d_in[2];
  const float* Wk = (const float*)d_in[3];
  const float* Wv = (const float*)d_in[4];
  const float* Wo = (const float*)d_in[5];
  const int* stp = (const int*)d_in[6];
  float* out = (float*)d_out;

  const size_t MS = (size_t)B_ * S_;  // 8192
  f16* xh = (f16*)d_ws;                         // 32MB
  f16* wqt = xh + MS * D_;                      // wqt|wkt|wvt|wot contiguous, 32MB
  f16* wkt = wqt + (size_t)D_ * D_;
  f16* wvt = wkt + (size_t)D_ * D_;
  f16* wot = wvt + (size_t)D_ * D_;
  f16* qkv = wot + (size_t)D_ * D_;             // 8192 x 6144 f16, ~100MB
  float2* tab = (float2*)(qkv + MS * (size_t)QKV_ST);
  f16* vt2 = xh;  // reuse: x consumed after the QKV GEMMs

  cvt_f32_to_f16<<<16384, 256, 0, stream>>>(x, xh, (long)(MS * D_));
  wtrans4<<<dim3(4096, 4), 256, 0, stream>>>(Wq, Wk, Wv, Wo, wqt);
  // 3 separate N=2048 GEMMs (R10: fused N=6144 was 823 TF vs ~1100 here),
  // writing into the strided qkv buffer (ldc=6144) to keep the fused layout.
  gemm8<f16><<<256, 512, 0, stream>>>(xh, wqt, qkv, 8192, 2048, 2048, 2048, QKV_ST);
  gemm8<f16><<<256, 512, 0, stream>>>(xh, wkt, qkv + 2048, 8192, 2048, 2048, 2048, QKV_ST);
  gemm8<f16><<<256, 512, 0, stream>>>(xh, wvt, qkv + 4096, 8192, 2048, 2048, 2048, QKV_ST);
  rope_table<<<512, 256, 0, stream>>>(tab, stp);
  // K roped in place (qkv cols 2048-4095); Q-RoPE fused into attn.
  rope_apply_k<<<4096, 256, 0, stream>>>(qkv, tab, (long)(MS * 1024));
  vtrans2<<<dim3(32, 64), 256, 0, stream>>>(qkv, vt2);
  // attn reads Q/K from qkv, writes O into qkv's Q columns
  attn<<<256, 512, 0, stream>>>(qkv, vt2, tab);
  // Wo GEMM: A = qkv Q-columns (lda=6144)
  gemm8<float><<<256, 512, 0, stream>>>(qkv, wot, out, 8192, 2048, 2048, QKV_ST, 2048);
}

// Round 13
// 457.126 us; speedup vs baseline: 1.0260x; 1.0018x over previous
//
#include <hip/hip_runtime.h>
#include <hip/hip_fp16.h>

typedef _Float16 f16;
typedef __attribute__((ext_vector_type(2))) _Float16 f16x2;
typedef __attribute__((ext_vector_type(4))) _Float16 f16x4v;
typedef __attribute__((ext_vector_type(8))) _Float16 f16x8;
typedef __attribute__((ext_vector_type(4))) float f32x4;
typedef __attribute__((ext_vector_type(4))) int i32x4;

#define DEV __device__ __forceinline__

static constexpr int S_ = 2048;
static constexpr int D_ = 2048;
static constexpr int H_ = 16;
static constexpr int HD_ = 128;
static constexpr int B_ = 4;
static constexpr int QKV_ST = 6144;  // fused qkv row stride (Q|K|V)

typedef const __attribute__((address_space(1))) void* gptr_t;
typedef __attribute__((address_space(3))) void* lptr_t;

// async global->LDS, 16B per lane. LDS dest must be wave-uniform; HW writes
// dest + lane*16 (m104 semantics). Compiler manages m0.
DEV void gl_lds16(const void* gsrc, void* lds) {
  __builtin_amdgcn_global_load_lds((gptr_t)gsrc, (lptr_t)lds, 16, 0, 0);
}

// f32 pair -> packed f16x2 bits (v_cvt_pkrtz_f16_f32)
DEV int cvt_pk_i32(float a, float b) {
  return __builtin_bit_cast(int, __builtin_amdgcn_cvt_pkrtz(a, b));
}

__global__ __launch_bounds__(256) void cvt_f32_to_f16(const float* __restrict__ in,
                                                      f16* __restrict__ out, long n) {
  long i0 = ((long)blockIdx.x * 256 + threadIdx.x) * 4;
  long stride = (long)gridDim.x * 256 * 4;
  for (long i = i0; i < n; i += stride) {
    float4 v = *(const float4*)(in + i);
    f16x4v o;
    o[0] = (f16)v.x; o[1] = (f16)v.y; o[2] = (f16)v.z; o[3] = (f16)v.w;
    *(f16x4v*)(out + i) = o;
  }
}

// W (2048 x 2048, row-major K x N) -> Wt (N x K) fp16; 4 weights, one launch.
__global__ __launch_bounds__(256) void wtrans4(const float* __restrict__ W0, const float* __restrict__ W1,
                                               const float* __restrict__ W2, const float* __restrict__ W3,
                                               f16* __restrict__ Wt) {
  __shared__ float tile[32][33];
  int wi = blockIdx.y;
  const float* W = wi == 0 ? W0 : wi == 1 ? W1 : wi == 2 ? W2 : W3;
  f16* dst = Wt + (size_t)wi * D_ * D_;
  int bx = blockIdx.x & 63, by = blockIdx.x >> 6;
  int r0 = by << 5, c0 = bx << 5;
  int tx = threadIdx.x & 31, ty = threadIdx.x >> 5;
#pragma unroll
  for (int i = 0; i < 4; i++) {
    int r = ty + i * 8;
    tile[r][tx] = W[(size_t)(r0 + r) * D_ + c0 + tx];
  }
  __syncthreads();
#pragma unroll
  for (int i = 0; i < 4; i++) {
    int r = ty + i * 8;
    dst[(size_t)(c0 + r) * D_ + r0 + tx] = (f16)tile[tx][r];
  }
}

// swizzled LDS fragment read: [128][64] f16 half-tile, st_16x32 XOR swizzle.
DEV f16x8 lds_frag(const f16* half, int row, int s, int lg) {
  int byte = row * 128 + s * 64 + lg * 16;
  byte ^= (row & 4) << 3;  // ^32B when row bit2 set (st_16x32)
  return *(const f16x8*)((const char*)half + byte);
}

// C = A(MxK, row stride lda) * Bt(NxK)^T ; C row stride ldc. 256x256 tile,
// BK=64, 8 waves, 512 thr, m201-style schedule.
// MULTI-SUBGROUP fusion (R12 lesson): plain N=2048 launches have grid=256
// = 1 block/CU -> 8-wave barrier lockstep, no phase diversity, MfmaUtil
// ~44% (m233: 2-phase stall ~72%). Launching 3 GEMMs sharing A as ONE
// grid of 3*nwg blocks: subgroup s = bid/nwg picks B/C offsets, inner
// mapping unchanged -> 2 blocks/CU resident (64KB LDS cap), and same-
// (by,bx) blocks across subgroups share the A tile in L2. Unlike R10's
// N=6144 fusion (which changed tiling: 823 TF), per-K-step footprint
// stays A 128KB + B 3x256KB < 4MB L2.
template <typename CT>
__global__ __launch_bounds__(512, 2) void gemm8(const f16* __restrict__ A, const f16* __restrict__ Bt,
                                                CT* __restrict__ C, int M, int N, int K,
                                                int lda, int ldc, long subB, long subC) {
  __shared__ alignas(16) f16 As[2][2][128 * 64];
  __shared__ alignas(16) f16 Bs[2][2][128 * 64];
  int nbx = N >> 8;
  int nwg = (M >> 8) * nbx;  // per-subgroup wg count (%8==0; ours: 256)
  int bid = blockIdx.x;
  int wi = bid / nwg;                            // subgroup (0 if plain)
  int bidl = bid - wi * nwg;
  Bt += (size_t)wi * subB;
  C += (size_t)wi * subC;
  int wg = (bidl & 7) * (nwg >> 3) + (bidl >> 3);  // XCD-contiguous chunks
  int bx = wg % nbx, by = wg / nbx;
  int tid = threadIdx.x, w = tid >> 6, l = tid & 63;
  int wm = w >> 2, wn = w & 3, lg = l >> 4, ln = l & 15;
  int nt = K >> 6;
  const f16* Ab = A + (size_t)(by * 256) * lda;
  const f16* Bb = Bt + (size_t)(bx * 256) * K;

  // stage one [128][64] half-tile: linear LDS dest, inverse-swizzled source.
  auto stageA = [&](const f16* src0, int kt, f16* dst) {
#pragma unroll
    for (int j = 0; j < 2; j++) {
      int c = j * 8 + w;                       // 1KB chunk
      int row = c * 8 + (l >> 3);
      int scol = ((l & 7) * 8) ^ ((row & 4) << 2);
      gl_lds16(src0 + (size_t)row * lda + kt * 64 + scol, (char*)dst + c * 1024);
    }
  };
  auto stageB = [&](const f16* src0, int kt, f16* dst) {
#pragma unroll
    for (int j = 0; j < 2; j++) {
      int c = j * 8 + w;                       // 1KB chunk
      int row = c * 8 + (l >> 3);
      int scol = ((l & 7) * 8) ^ ((row & 4) << 2);
      gl_lds16(src0 + (size_t)row * K + kt * 64 + scol, (char*)dst + c * 1024);
    }
  };

  f32x4 acc[8][4] = {};

  // prologue: tile0 A+B, tile1 B (A(t+1) staged at p0/p1, B(t+2) at p2/p3)
  stageA(Ab, 0, As[0][0]);
  stageA(Ab + (size_t)128 * lda, 0, As[0][1]);
  stageB(Bb, 0, Bs[0][0]);
  stageB(Bb + (size_t)128 * K, 0, Bs[0][1]);
  if (nt > 1) {
    stageB(Bb, 1, Bs[1][0]);
    stageB(Bb + (size_t)128 * K, 1, Bs[1][1]);
  }

  for (int t = 0; t < nt; t++) {
    // tile-entry drain: A(t)+B(t) landed for every wave, then collective barrier
    if (t + 2 < nt) asm volatile("s_waitcnt vmcnt(4)" ::: "memory");
    else            asm volatile("s_waitcnt vmcnt(0)" ::: "memory");
    __builtin_amdgcn_s_barrier();
    asm volatile("" ::: "memory");
    const f16* Ah = As[t & 1][wm];
    const f16* Bh = Bs[t & 1][wn >> 1];
    int br0 = (wn & 1) * 64;
    f16x8 a[4], b0[4], b1[4];
    // ---- p0: (mh0, k0); stage A(t+1) h0
#pragma unroll
    for (int i = 0; i < 4; i++) a[i] = lds_frag(Ah, i * 16 + ln, 0, lg);
#pragma unroll
    for (int i = 0; i < 4; i++) b0[i] = lds_frag(Bh, br0 + i * 16 + ln, 0, lg);
    if (t + 1 < nt) stageA(Ab, t + 1, As[(t + 1) & 1][0]);
    __builtin_amdgcn_s_barrier();
    asm volatile("" ::: "memory");
    __builtin_amdgcn_s_setprio(1);
#pragma unroll
    for (int mi = 0; mi < 4; mi++)
#pragma unroll
      for (int ni = 0; ni < 4; ni++)
        acc[mi][ni] = __builtin_amdgcn_mfma_f32_16x16x32_f16(a[mi], b0[ni], acc[mi][ni], 0, 0, 0);
    __builtin_amdgcn_s_setprio(0);
    __builtin_amdgcn_s_barrier();
    asm volatile("" ::: "memory");
    // ---- p1: (mh0, k1); stage A(t+1) h1
#pragma unroll
    for (int i = 0; i < 4; i++) a[i] = lds_frag(Ah, i * 16 + ln, 1, lg);
#pragma unroll
    for (int i = 0; i < 4; i++) b1[i] = lds_frag(Bh, br0 + i * 16 + ln, 1, lg);
    if (t + 1 < nt) stageA(Ab + (size_t)128 * lda, t + 1, As[(t + 1) & 1][1]);
    __builtin_amdgcn_s_barrier();
    asm volatile("" ::: "memory");
    __builtin_amdgcn_s_setprio(1);
#pragma unroll
    for (int mi = 0; mi < 4; mi++)
#pragma unroll
      for (int ni = 0; ni < 4; ni++)
        acc[mi][ni] = __builtin_amdgcn_mfma_f32_16x16x32_f16(a[mi], b1[ni], acc[mi][ni], 0, 0, 0);
    __builtin_amdgcn_s_setprio(0);
    __builtin_amdgcn_s_barrier();
    asm volatile("" ::: "memory");
    // ---- p2: (mh1, k0); B regs held; B LDS region free -> stage B(t+2) h0
#pragma unroll
    for (int i = 0; i < 4; i++) a[i] = lds_frag(Ah, 64 + i * 16 + ln, 0, lg);
    if (t + 2 < nt) stageB(Bb, t + 2, Bs[t & 1][0]);
    __builtin_amdgcn_s_barrier();
    asm volatile("" ::: "memory");
    __builtin_amdgcn_s_setprio(1);
#pragma unroll
    for (int mi = 0; mi < 4; mi++)
#pragma unroll
      for (int ni = 0; ni < 4; ni++)
        acc[mi + 4][ni] = __builtin_amdgcn_mfma_f32_16x16x32_f16(a[mi], b0[ni], acc[mi + 4][ni], 0, 0, 0);
    __builtin_amdgcn_s_setprio(0);
    __builtin_amdgcn_s_barrier();
    asm volatile("" ::: "memory");
    // ---- p3: (mh1, k1); stage B(t+2) h1
#pragma unroll
    for (int i = 0; i < 4; i++) a[i] = lds_frag(Ah, 64 + i * 16 + ln, 1, lg);
    if (t + 2 < nt) stageB(Bb + (size_t)128 * K, t + 2, Bs[t & 1][1]);
    __builtin_amdgcn_s_barrier();
    asm volatile("" ::: "memory");
    __builtin_amdgcn_s_setprio(1);
#pragma unroll
    for (int mi = 0; mi < 4; mi++)
#pragma unroll
      for (int ni = 0; ni < 4; ni++)
        acc[mi + 4][ni] = __builtin_amdgcn_mfma_f32_16x16x32_f16(a[mi], b1[ni], acc[mi + 4][ni], 0, 0, 0);
    __builtin_amdgcn_s_setprio(0);
    __builtin_amdgcn_s_barrier();
    asm volatile("" ::: "memory");
  }

  int row0 = by * 256 + wm * 128;
  int col0 = bx * 256 + wn * 64;
#pragma unroll
  for (int mi = 0; mi < 8; mi++)
#pragma unroll
    for (int ni = 0; ni < 4; ni++)
#pragma unroll
      for (int r4 = 0; r4 < 4; r4++) {
        int row = row0 + mi * 16 + lg * 4 + r4;
        int col = col0 + ni * 16 + ln;
        float o = acc[mi][ni][r4];
        if constexpr (sizeof(CT) == 2) {
          float oo = __shfl_xor(o, 1);
          if (!(ln & 1)) {
            f16x2 pp; pp[0] = (f16)o; pp[1] = (f16)oo;
            *(f16x2*)(&C[(size_t)row * ldc + col]) = pp;
          }
        } else {
          C[(size_t)row * ldc + col] = o;
        }
      }
}

__global__ __launch_bounds__(256) void rope_table(float2* __restrict__ tab, const int* __restrict__ st) {
  int i = blockIdx.x * 256 + threadIdx.x;  // S*64 entries
  int s = i >> 6, j = i & 63;
  float theta = powf(10000.f, -(float)j / 64.f);
  float ang = (float)(s + st[0]) * theta;
  tab[i] = make_float2(cosf(ang), sinf(ang));
}

// RoPE over the K columns (2048..4095) of the fused qkv buffer, in place.
__global__ __launch_bounds__(256) void rope_apply_k(f16* __restrict__ QKV, const float2* __restrict__ tab,
                                                    long npairs) {
  long i0 = (long)blockIdx.x * 256 + threadIdx.x;
  long stride = (long)gridDim.x * 256;
  for (long p = i0; p < npairs; p += stride) {
    long row = p >> 10;            // 1024 K-pairs per row
    int jp = (int)(p & 1023);
    int s = (int)(row & (S_ - 1));
    float2 cs = tab[s * 64 + (jp & 63)];
    f16* px = QKV + row * QKV_ST + 2048 + 2 * jp;
    f16x2 v = *(const f16x2*)px;
    float xe = (float)v[0], xo = (float)v[1];
    float re = xe * cs.x - xo * cs.y;
    float ro = xe * cs.y + xo * cs.x;
    f16x2 o; o[0] = (f16)re; o[1] = (f16)ro;
    *(f16x2*)px = o;
  }
}

// V (qkv cols 4096+) -> VT2 fragment-linear with the ZERO-SHUFFLE k<->kv
// mapping: per (bh, kv-tile t, nj, kk) one 1KB chunk; lane l=(lg*16+ln),
// element e owns V[d = nj*16 + ln][kv = t*64 + 16*(2kk+(e>>2)) + 4lg + (e&3)].
// Sigma matches QK^T's lane-local layout so attn's PV B-operand is a pure
// in-register pack. Both A (V) and B (P) use this sigma.
__global__ __launch_bounds__(256) void vtrans2(const f16* __restrict__ QKV, f16* __restrict__ VT2) {
  __shared__ alignas(16) f16 tile[64 * 128];  // [kv][d], 16B-chunk XOR-swizzled
  int t = blockIdx.x, bh = blockIdx.y, b = bh >> 4, h = bh & 15;
  int tid = threadIdx.x, w = tid >> 6, l = tid & 63, lg = l >> 4, ln = l & 15;
  const f16* src = QKV + (size_t)(b * S_ + t * 64) * QKV_ST + 4096 + h * HD_;
#pragma unroll
  for (int i = 0; i < 4; i++) {
    int idx = i * 256 + tid;            // 16B-unit index
    int r = idx >> 4, c8 = idx & 15;
    int c8s = c8 ^ ((r >> 3) & 3);      // swizzle: both sides use same XOR
    *(f16x8*)(&tile[r * 128 + c8s * 8]) = *(const f16x8*)(src + (size_t)r * QKV_ST + c8 * 8);
  }
  __syncthreads();
  f16* dst = VT2 + (size_t)(bh * 32 + t) * 16 * 512;
#pragma unroll
  for (int ci = 0; ci < 4; ci++) {
    int c = w * 4 + ci;                 // chunk = nj*2 + kk
    int nj = c >> 1, kk = c & 1;
    f16x8 v;
#pragma unroll
    for (int e = 0; e < 8; e++) {
      int r = 16 * (2 * kk + (e >> 2)) + 4 * lg + (e & 3);  // sigma(k-slot)
      int col = nj * 16 + ln;
      int c8s = (col >> 3) ^ ((r >> 3) & 3);
      v[e] = tile[r * 128 + c8s * 8 + (col & 7)];
    }
    *(f16x8*)(dst + (size_t)c * 512 + l * 8) = v;
  }
}

// flash attention, causal. 8 waves x 16 q-rows (QBLK=128), KV tile = 64,
// TWO KV-TILES PER BARRIER PERIOD: kls[2][2][64*128] (64KB, 2 blocks/CU).
// R11 config (best measured attn, 127.4us; R12 heavy-wave 2x-ILP variant
// was 141.5us at 1 block/CU -> reverted). SWAPPED QK^T; lane-local
// softmax; ZERO-SHUFFLE PV (VT2 sigma); Q-RoPE fused into Q load; V
// chunks 0-7 after QK^T; UNIFORM blocks via causal pairing (15-u, u).
// Q/K read from fused qkv (stride 6144); O written back into Q columns.
// lsum quad-reduce deferred to epilogue. log2 scores; T13 defer-max THR=8.
__global__ __launch_bounds__(512, 4) void attn(f16* __restrict__ QKV, const f16* __restrict__ VT2,
                                               const float2* __restrict__ tab) {
  __shared__ alignas(16) f16 kls[2][2][64 * 128];
  int id = blockIdx.x;                   // 512 blocks
  int r8 = id & 7, j = id >> 3;          // j: 0..63 per XCD-residue
  int u = j & 7, g = j >> 3;             // u: pair id, g: bh group 0..7
  int bh = r8 + (g << 3);                // 8 bh's per XCD residue, bh-major
  int b = bh >> 4, h = bh & 15;
  int tid = threadIdx.x, w = tid >> 6, l = tid & 63, lg = l >> 4, ln = l & 15;

  const float QSCALE = 0.12751744910173355f;  // log2(e)/sqrt(128)
  const f16* kp = QKV + (size_t)(b * S_) * QKV_ST + 2048 + h * HD_;
  const f16* vp2 = VT2 + (size_t)bh * 32 * 16 * 512;

  auto stageK = [&](int buf, int half, int kv0) {
#pragma unroll
    for (int jj = 0; jj < 2; jj++) {
      int i = jj * 8 + w;
      int byte = i * 1024 + 16 * l;
      int r = byte >> 8;                       // row 0..63
      int c = (((byte >> 4) & 15) - r) & 15;   // inverse additive swizzle
      gl_lds16(kp + (size_t)(kv0 + r) * QKV_ST + c * 8, (char*)kls[buf][half] + i * 1024);
    }
  };

#pragma unroll 1
  for (int pi = 0; pi < 2; pi++) {
    int qsel = pi ? u : 15 - u;          // heavy pass first (K range in L2)
    int q0 = qsel << 7;
    int qrow = q0 + w * 16 + ln;         // this lane's q row (output column)
    f16* qp = QKV + (size_t)(b * S_ + qrow) * QKV_ST + h * HD_;
    const float2* tq = tab + (size_t)qrow * 64;
    f16x8 qf[4];
#pragma unroll
    for (int kc = 0; kc < 4; kc++) {
      f16x8 q = *(const f16x8*)(qp + kc * 32 + lg * 8);
#pragma unroll
      for (int p = 0; p < 4; p++) {
        float2 cs = tq[kc * 16 + lg * 4 + p];
        float e0 = (float)q[2 * p], e1 = (float)q[2 * p + 1];
        q[2 * p] = (f16)((e0 * cs.x - e1 * cs.y) * QSCALE);
        q[2 * p + 1] = (f16)((e0 * cs.y + e1 * cs.x) * QSCALE);
      }
      qf[kc] = q;
    }

    float m = -1e30f, lsum = 0.f;        // lsum: LANE-LOCAL partial
    f32x4 oacc[8] = {};                  // O^T[d = nj*16 + lg*4 + r4][q = ln]

    int np = qsel + 1;                   // periods; nt64 = 2*qsel+2 tiles
    int nt64 = 2 * qsel + 2;
    if (pi) __syncthreads();             // kls readers from prev pass done
    stageK(0, 0, 0);                     // prologue: period 0 (tiles 0,1)
    stageK(0, 1, 64);
#pragma unroll 1
    for (int p = 0; p < np; p++) {
      __syncthreads();  // drains period-p staging; all waves done with buf
      if (p + 1 < np) {
        stageK((p + 1) & 1, 0, (2 * p + 2) << 6);
        stageK((p + 1) & 1, 1, (2 * p + 3) << 6);
      }
#pragma unroll 1
      for (int ii = 0; ii < 2; ii++) {
        int t = 2 * p + ii;
        int kv0 = t << 6;
        // wave-uniform skip: this wave's rows all precede the tile
        if (kv0 > q0 + w * 16 + 15) continue;
        const f16* kb = kls[p & 1][ii];
        const f16* vt = vp2 + (size_t)t * 16 * 512;

        // S^T = K Q^T: sf[ni][r4] = S[kv = kv0 + ni*16 + lg*4 + r4][q = ln]
        f32x4 sf[4];
        __builtin_amdgcn_s_setprio(1);
#pragma unroll
        for (int ni = 0; ni < 4; ni++) {
          int n = ni * 16 + ln;
          f32x4 s = {0.f, 0.f, 0.f, 0.f};
#pragma unroll
          for (int kc = 0; kc < 4; kc++) {
            int mch = kc * 4 + lg;
            f16x8 kf = *(const f16x8*)(&kb[n * 128 + (((mch + n) & 15) << 3)]);
            s = __builtin_amdgcn_mfma_f32_16x16x32_f16(kf, qf[kc], s, 0, 0, 0);
          }
          sf[ni] = s;
        }
        __builtin_amdgcn_s_setprio(0);

        // V chunks 0-7 issued now; latency hides under mask+softmax
        f16x8 vfa[8];
#pragma unroll
        for (int c = 0; c < 8; c++) vfa[c] = *(const f16x8*)(vt + c * 512 + l * 8);

        if (t >= nt64 - 2) {  // only the two diagonal-adjacent tiles mask
#pragma unroll
          for (int ni = 0; ni < 4; ni++) {
            int kvg = kv0 + ni * 16 + lg * 4;
#pragma unroll
            for (int r4 = 0; r4 < 4; r4++)
              if (kvg + r4 > qrow) sf[ni][r4] = -1e30f;
          }
        }
        // online softmax (log2 domain), lane-local + 2 shfl (max only)
        float pm = fmaxf(fmaxf(fmaxf(sf[0][0], sf[0][1]), fmaxf(sf[0][2], sf[0][3])),
                         fmaxf(fmaxf(sf[1][0], sf[1][1]), fmaxf(sf[1][2], sf[1][3])));
        pm = fmaxf(pm, fmaxf(fmaxf(fmaxf(sf[2][0], sf[2][1]), fmaxf(sf[2][2], sf[2][3])),
                             fmaxf(fmaxf(sf[3][0], sf[3][1]), fmaxf(sf[3][2], sf[3][3]))));
        pm = fmaxf(pm, __shfl_xor(pm, 16));
        pm = fmaxf(pm, __shfl_xor(pm, 32));
        // T13 defer-max: keep old m while tile max hasn't outgrown it by >8
        float scl = 1.f;
        bool defer = __all(pm <= m + 8.f);
        if (!defer) {
          float mn = fmaxf(m, pm);
          scl = __builtin_amdgcn_exp2f(m - mn);
          m = mn;
        }
        float rsum = 0.f;
#pragma unroll
        for (int ni = 0; ni < 4; ni++)
#pragma unroll
          for (int r4 = 0; r4 < 4; r4++) {
            float pv = __builtin_amdgcn_exp2f(sf[ni][r4] - m);
            sf[ni][r4] = pv;
            rsum += pv;
          }
        lsum = lsum * scl + rsum;  // lane-local; cross-lane in epilogue

        // rescale O^T (skipped on defer tiles)
        if (!defer) {
#pragma unroll
          for (int nj = 0; nj < 8; nj++)
#pragma unroll
            for (int r4 = 0; r4 < 4; r4++) oacc[nj][r4] *= scl;
        }

        // ZERO-SHUFFLE pack: pa[kk] = [sf[2kk][0..3], sf[2kk+1][0..3]]
        f16x8 pa[2];
#pragma unroll
        for (int kk = 0; kk < 2; kk++) {
          i32x4 wv;
          wv.x = cvt_pk_i32(sf[2 * kk][0], sf[2 * kk][1]);
          wv.y = cvt_pk_i32(sf[2 * kk][2], sf[2 * kk][3]);
          wv.z = cvt_pk_i32(sf[2 * kk + 1][0], sf[2 * kk + 1][1]);
          wv.w = cvt_pk_i32(sf[2 * kk + 1][2], sf[2 * kk + 1][3]);
          pa[kk] = __builtin_bit_cast(f16x8, wv);
        }

        __builtin_amdgcn_s_setprio(1);
        // PV first half: nj 0-3 from pre-issued vfa (chunk = nj*2+kk)
#pragma unroll
        for (int kk = 0; kk < 2; kk++)
#pragma unroll
          for (int nj = 0; nj < 4; nj++)
            oacc[nj] = __builtin_amdgcn_mfma_f32_16x16x32_f16(vfa[nj * 2 + kk], pa[kk], oacc[nj], 0, 0, 0);
        // PV second half: nj 4-7, in-loop batches of 4
#pragma unroll
        for (int njb = 0; njb < 2; njb++) {
          f16x8 vf[4];
#pragma unroll
          for (int jj = 0; jj < 2; jj++)
#pragma unroll
            for (int kk = 0; kk < 2; kk++)
              vf[jj * 2 + kk] = *(const f16x8*)(vt + (size_t)(((4 + njb * 2 + jj) * 2 + kk) * 512) + l * 8);
#pragma unroll
          for (int kk = 0; kk < 2; kk++)
#pragma unroll
            for (int jj = 0; jj < 2; jj++)
              oacc[4 + njb * 2 + jj] = __builtin_amdgcn_mfma_f32_16x16x32_f16(
                  vf[jj * 2 + kk], pa[kk], oacc[4 + njb * 2 + jj], 0, 0, 0);
        }
        __builtin_amdgcn_s_setprio(0);
      }
    }

    // per-pass epilogue: quad-reduce lane-local lsum; write O into the Q
    // columns of qkv (this block's own rows, already consumed).
    lsum += __shfl_xor(lsum, 16);
    lsum += __shfl_xor(lsum, 32);
    float inv = 1.f / lsum;
#pragma unroll
    for (int nj = 0; nj < 8; nj++) {
      f16x4v ov;
#pragma unroll
      for (int r4 = 0; r4 < 4; r4++) ov[r4] = (f16)(oacc[nj][r4] * inv);
      *(f16x4v*)(qp + nj * 16 + lg * 4) = ov;
    }
  }
}

extern "C" void kernel_launch(void* const* d_in, const int* in_sizes, int n_in,
                              void* d_out, int out_size, void* d_ws, size_t ws_size,
                              hipStream_t stream) {
  (void)in_sizes; (void)n_in; (void)out_size; (void)ws_size;
  const float* x = (const float*)d_in[0];
  // d_in[1] = mask (causal, reproduced analytically)
  const float* Wq = (const float*)d_in[2];
  const float* Wk = (const float*)d_in[3];
  const float* Wv = (const float*)d_in[4];
  const float* Wo = (const float*)d_in[5];
  const int* stp = (const int*)d_in[6];
  float* out = (float*)d_out;

  const size_t MS = (size_t)B_ * S_;  // 8192
  f16* xh = (f16*)d_ws;                         // 32MB
  f16* wqt = xh + MS * D_;                      // wqt|wkt|wvt|wot contiguous, 32MB
  f16* wot = wqt + (size_t)3 * D_ * D_;
  f16* qkv = wot + (size_t)D_ * D_;             // 8192 x 6144 f16, ~100MB
  float2* tab = (float2*)(qkv + MS * (size_t)QKV_ST);
  f16* vt2 = xh;  // reuse: x consumed after the QKV GEMMs

  cvt_f32_to_f16<<<16384, 256, 0, stream>>>(x, xh, (long)(MS * D_));
  wtrans4<<<dim3(4096, 4), 256, 0, stream>>>(Wq, Wk, Wv, Wo, wqt);
  // ONE 768-block launch = 3 subgroup GEMMs (Q,K,V) sharing A:
  // 2 blocks/CU resident (phase diversity) + A-tile L2 sharing.
  gemm8<f16><<<768, 512, 0, stream>>>(xh, wqt, qkv, 8192, 2048, 2048, 2048, QKV_ST,
                                      (long)D_ * D_, 2048);
  rope_table<<<512, 256, 0, stream>>>(tab, stp);
  // K roped in place (qkv cols 2048-4095); Q-RoPE fused into attn.
  rope_apply_k<<<4096, 256, 0, stream>>>(qkv, tab, (long)(MS * 1024));
  vtrans2<<<dim3(32, 64), 256, 0, stream>>>(qkv, vt2);
  // attn reads Q/K from qkv, writes O into qkv's Q columns
  attn<<<512, 512, 0, stream>>>(qkv, vt2, tab);
  // Wo GEMM: A = qkv Q-columns (lda=6144)
  gemm8<float><<<256, 512, 0, stream>>>(qkv, wot, out, 8192, 2048, 2048, QKV_ST, 2048, 0, 0);
}

// Round 14
// 451.877 us; speedup vs baseline: 1.0379x; 1.0116x over previous
//
#include <hip/hip_runtime.h>
#include <hip/hip_fp16.h>

typedef _Float16 f16;
typedef __attribute__((ext_vector_type(2))) _Float16 f16x2;
typedef __attribute__((ext_vector_type(4))) _Float16 f16x4v;
typedef __attribute__((ext_vector_type(8))) _Float16 f16x8;
typedef __attribute__((ext_vector_type(4))) float f32x4;
typedef __attribute__((ext_vector_type(4))) int i32x4;

#define DEV __device__ __forceinline__

static constexpr int S_ = 2048;
static constexpr int D_ = 2048;
static constexpr int H_ = 16;
static constexpr int HD_ = 128;
static constexpr int B_ = 4;
static constexpr int QKV_ST = 6144;  // fused qkv row stride (Q|K|V)

typedef const __attribute__((address_space(1))) void* gptr_t;
typedef __attribute__((address_space(3))) void* lptr_t;

// async global->LDS, 16B per lane. LDS dest must be wave-uniform; HW writes
// dest + lane*16 (m104 semantics). Compiler manages m0.
DEV void gl_lds16(const void* gsrc, void* lds) {
  __builtin_amdgcn_global_load_lds((gptr_t)gsrc, (lptr_t)lds, 16, 0, 0);
}

// f32 pair -> packed f16x2 bits (v_cvt_pkrtz_f16_f32)
DEV int cvt_pk_i32(float a, float b) {
  return __builtin_bit_cast(int, __builtin_amdgcn_cvt_pkrtz(a, b));
}

__global__ __launch_bounds__(256) void cvt_f32_to_f16(const float* __restrict__ in,
                                                      f16* __restrict__ out, long n) {
  long i0 = ((long)blockIdx.x * 256 + threadIdx.x) * 4;
  long stride = (long)gridDim.x * 256 * 4;
  for (long i = i0; i < n; i += stride) {
    float4 v = *(const float4*)(in + i);
    f16x4v o;
    o[0] = (f16)v.x; o[1] = (f16)v.y; o[2] = (f16)v.z; o[3] = (f16)v.w;
    *(f16x4v*)(out + i) = o;
  }
}

// W (2048 x 2048, row-major K x N) -> Wt (N x K) fp16; 4 weights, one launch.
__global__ __launch_bounds__(256) void wtrans4(const float* __restrict__ W0, const float* __restrict__ W1,
                                               const float* __restrict__ W2, const float* __restrict__ W3,
                                               f16* __restrict__ Wt) {
  __shared__ float tile[32][33];
  int wi = blockIdx.y;
  const float* W = wi == 0 ? W0 : wi == 1 ? W1 : wi == 2 ? W2 : W3;
  f16* dst = Wt + (size_t)wi * D_ * D_;
  int bx = blockIdx.x & 63, by = blockIdx.x >> 6;
  int r0 = by << 5, c0 = bx << 5;
  int tx = threadIdx.x & 31, ty = threadIdx.x >> 5;
#pragma unroll
  for (int i = 0; i < 4; i++) {
    int r = ty + i * 8;
    tile[r][tx] = W[(size_t)(r0 + r) * D_ + c0 + tx];
  }
  __syncthreads();
#pragma unroll
  for (int i = 0; i < 4; i++) {
    int r = ty + i * 8;
    dst[(size_t)(c0 + r) * D_ + r0 + tx] = (f16)tile[tx][r];
  }
}

// swizzled LDS fragment read: [128][64] f16 half-tile.
// FULL 3-bit XOR swizzle (R13 fix): bank-group of a 16B slot is
// (byte>>4)&7 = (s*4+lg)&7, independent of ln -- the old 1-bit
// ((row&4)<<3) swizzle left an 8-WAY conflict (16 lanes -> 2 groups;
// measured 1.9e7 conflict cycles, MfmaUtil 36%). XOR row bits 0-2 into
// byte bits 4-6: group = (s*4+lg)^(ln&7) -> 16 lanes cover all 8 groups
// twice = 2-way = free (m136; G4 prescription).
DEV f16x8 lds_frag(const f16* half, int row, int s, int lg) {
  int byte = row * 128 + s * 64 + lg * 16;
  byte ^= (row & 7) << 4;
  return *(const f16x8*)((const char*)half + byte);
}

// C = A(MxK, row stride lda) * Bt(NxK)^T ; C row stride ldc. 256x256 tile,
// BK=64, 8 waves, 512 thr, m201-style schedule. Multi-subgroup fusion:
// subgroup s = bid/nwg picks B/C offsets (QKV GEMMs share A in one grid).
template <typename CT>
__global__ __launch_bounds__(512, 2) void gemm8(const f16* __restrict__ A, const f16* __restrict__ Bt,
                                                CT* __restrict__ C, int M, int N, int K,
                                                int lda, int ldc, long subB, long subC) {
  __shared__ alignas(16) f16 As[2][2][128 * 64];
  __shared__ alignas(16) f16 Bs[2][2][128 * 64];
  int nbx = N >> 8;
  int nwg = (M >> 8) * nbx;  // per-subgroup wg count (%8==0; ours: 256)
  int bid = blockIdx.x;
  int wi = bid / nwg;                            // subgroup (0 if plain)
  int bidl = bid - wi * nwg;
  Bt += (size_t)wi * subB;
  C += (size_t)wi * subC;
  int wg = (bidl & 7) * (nwg >> 3) + (bidl >> 3);  // XCD-contiguous chunks
  int bx = wg % nbx, by = wg / nbx;
  int tid = threadIdx.x, w = tid >> 6, l = tid & 63;
  int wm = w >> 2, wn = w & 3, lg = l >> 4, ln = l & 15;
  int nt = K >> 6;
  const f16* Ab = A + (size_t)(by * 256) * lda;
  const f16* Bb = Bt + (size_t)(bx * 256) * K;

  // stage one [128][64] half-tile: linear LDS dest (gl_lds16 requirement),
  // source slot = (l&7) ^ (row&7) -- same involution as lds_frag (rule #21).
  auto stageA = [&](const f16* src0, int kt, f16* dst) {
#pragma unroll
    for (int j = 0; j < 2; j++) {
      int c = j * 8 + w;                       // 1KB chunk
      int row = c * 8 + (l >> 3);
      int scol = ((l & 7) ^ (row & 7)) << 3;   // elems (16B units)
      gl_lds16(src0 + (size_t)row * lda + kt * 64 + scol, (char*)dst + c * 1024);
    }
  };
  auto stageB = [&](const f16* src0, int kt, f16* dst) {
#pragma unroll
    for (int j = 0; j < 2; j++) {
      int c = j * 8 + w;                       // 1KB chunk
      int row = c * 8 + (l >> 3);
      int scol = ((l & 7) ^ (row & 7)) << 3;
      gl_lds16(src0 + (size_t)row * K + kt * 64 + scol, (char*)dst + c * 1024);
    }
  };

  f32x4 acc[8][4] = {};

  // prologue: tile0 A+B, tile1 B (A(t+1) staged at p0/p1, B(t+2) at p2/p3)
  stageA(Ab, 0, As[0][0]);
  stageA(Ab + (size_t)128 * lda, 0, As[0][1]);
  stageB(Bb, 0, Bs[0][0]);
  stageB(Bb + (size_t)128 * K, 0, Bs[0][1]);
  if (nt > 1) {
    stageB(Bb, 1, Bs[1][0]);
    stageB(Bb + (size_t)128 * K, 1, Bs[1][1]);
  }

  for (int t = 0; t < nt; t++) {
    // tile-entry drain: A(t)+B(t) landed for every wave, then collective barrier
    if (t + 2 < nt) asm volatile("s_waitcnt vmcnt(4)" ::: "memory");
    else            asm volatile("s_waitcnt vmcnt(0)" ::: "memory");
    __builtin_amdgcn_s_barrier();
    asm volatile("" ::: "memory");
    const f16* Ah = As[t & 1][wm];
    const f16* Bh = Bs[t & 1][wn >> 1];
    int br0 = (wn & 1) * 64;
    f16x8 a[4], b0[4], b1[4];
    // ---- p0: (mh0, k0); stage A(t+1) h0
#pragma unroll
    for (int i = 0; i < 4; i++) a[i] = lds_frag(Ah, i * 16 + ln, 0, lg);
#pragma unroll
    for (int i = 0; i < 4; i++) b0[i] = lds_frag(Bh, br0 + i * 16 + ln, 0, lg);
    if (t + 1 < nt) stageA(Ab, t + 1, As[(t + 1) & 1][0]);
    __builtin_amdgcn_s_barrier();
    asm volatile("" ::: "memory");
    __builtin_amdgcn_s_setprio(1);
#pragma unroll
    for (int mi = 0; mi < 4; mi++)
#pragma unroll
      for (int ni = 0; ni < 4; ni++)
        acc[mi][ni] = __builtin_amdgcn_mfma_f32_16x16x32_f16(a[mi], b0[ni], acc[mi][ni], 0, 0, 0);
    __builtin_amdgcn_s_setprio(0);
    __builtin_amdgcn_s_barrier();
    asm volatile("" ::: "memory");
    // ---- p1: (mh0, k1); stage A(t+1) h1
#pragma unroll
    for (int i = 0; i < 4; i++) a[i] = lds_frag(Ah, i * 16 + ln, 1, lg);
#pragma unroll
    for (int i = 0; i < 4; i++) b1[i] = lds_frag(Bh, br0 + i * 16 + ln, 1, lg);
    if (t + 1 < nt) stageA(Ab + (size_t)128 * lda, t + 1, As[(t + 1) & 1][1]);
    __builtin_amdgcn_s_barrier();
    asm volatile("" ::: "memory");
    __builtin_amdgcn_s_setprio(1);
#pragma unroll
    for (int mi = 0; mi < 4; mi++)
#pragma unroll
      for (int ni = 0; ni < 4; ni++)
        acc[mi][ni] = __builtin_amdgcn_mfma_f32_16x16x32_f16(a[mi], b1[ni], acc[mi][ni], 0, 0, 0);
    __builtin_amdgcn_s_setprio(0);
    __builtin_amdgcn_s_barrier();
    asm volatile("" ::: "memory");
    // ---- p2: (mh1, k0); B regs held; B LDS region free -> stage B(t+2) h0
#pragma unroll
    for (int i = 0; i < 4; i++) a[i] = lds_frag(Ah, 64 + i * 16 + ln, 0, lg);
    if (t + 2 < nt) stageB(Bb, t + 2, Bs[t & 1][0]);
    __builtin_amdgcn_s_barrier();
    asm volatile("" ::: "memory");
    __builtin_amdgcn_s_setprio(1);
#pragma unroll
    for (int mi = 0; mi < 4; mi++)
#pragma unroll
      for (int ni = 0; ni < 4; ni++)
        acc[mi + 4][ni] = __builtin_amdgcn_mfma_f32_16x16x32_f16(a[mi], b0[ni], acc[mi + 4][ni], 0, 0, 0);
    __builtin_amdgcn_s_setprio(0);
    __builtin_amdgcn_s_barrier();
    asm volatile("" ::: "memory");
    // ---- p3: (mh1, k1); stage B(t+2) h1
#pragma unroll
    for (int i = 0; i < 4; i++) a[i] = lds_frag(Ah, 64 + i * 16 + ln, 1, lg);
    if (t + 2 < nt) stageB(Bb + (size_t)128 * K, t + 2, Bs[t & 1][1]);
    __builtin_amdgcn_s_barrier();
    asm volatile("" ::: "memory");
    __builtin_amdgcn_s_setprio(1);
#pragma unroll
    for (int mi = 0; mi < 4; mi++)
#pragma unroll
      for (int ni = 0; ni < 4; ni++)
        acc[mi + 4][ni] = __builtin_amdgcn_mfma_f32_16x16x32_f16(a[mi], b1[ni], acc[mi + 4][ni], 0, 0, 0);
    __builtin_amdgcn_s_setprio(0);
    __builtin_amdgcn_s_barrier();
    asm volatile("" ::: "memory");
  }

  int row0 = by * 256 + wm * 128;
  int col0 = bx * 256 + wn * 64;
#pragma unroll
  for (int mi = 0; mi < 8; mi++)
#pragma unroll
    for (int ni = 0; ni < 4; ni++)
#pragma unroll
      for (int r4 = 0; r4 < 4; r4++) {
        int row = row0 + mi * 16 + lg * 4 + r4;
        int col = col0 + ni * 16 + ln;
        float o = acc[mi][ni][r4];
        if constexpr (sizeof(CT) == 2) {
          float oo = __shfl_xor(o, 1);
          if (!(ln & 1)) {
            f16x2 pp; pp[0] = (f16)o; pp[1] = (f16)oo;
            *(f16x2*)(&C[(size_t)row * ldc + col]) = pp;
          }
        } else {
          C[(size_t)row * ldc + col] = o;
        }
      }
}

__global__ __launch_bounds__(256) void rope_table(float2* __restrict__ tab, const int* __restrict__ st) {
  int i = blockIdx.x * 256 + threadIdx.x;  // S*64 entries
  int s = i >> 6, j = i & 63;
  float theta = powf(10000.f, -(float)j / 64.f);
  float ang = (float)(s + st[0]) * theta;
  tab[i] = make_float2(cosf(ang), sinf(ang));
}

// RoPE over the K columns (2048..4095) of the fused qkv buffer, in place.
__global__ __launch_bounds__(256) void rope_apply_k(f16* __restrict__ QKV, const float2* __restrict__ tab,
                                                    long npairs) {
  long i0 = (long)blockIdx.x * 256 + threadIdx.x;
  long stride = (long)gridDim.x * 256;
  for (long p = i0; p < npairs; p += stride) {
    long row = p >> 10;            // 1024 K-pairs per row
    int jp = (int)(p & 1023);
    int s = (int)(row & (S_ - 1));
    float2 cs = tab[s * 64 + (jp & 63)];
    f16* px = QKV + row * QKV_ST + 2048 + 2 * jp;
    f16x2 v = *(const f16x2*)px;
    float xe = (float)v[0], xo = (float)v[1];
    float re = xe * cs.x - xo * cs.y;
    float ro = xe * cs.y + xo * cs.x;
    f16x2 o; o[0] = (f16)re; o[1] = (f16)ro;
    *(f16x2*)px = o;
  }
}

// V (qkv cols 4096+) -> VT2 fragment-linear with the ZERO-SHUFFLE k<->kv
// mapping: per (bh, kv-tile t, nj, kk) one 1KB chunk; lane l=(lg*16+ln),
// element e owns V[d = nj*16 + ln][kv = t*64 + 16*(2kk+(e>>2)) + 4lg + (e&3)].
// Sigma matches QK^T's lane-local layout so attn's PV B-operand is a pure
// in-register pack. Both A (V) and B (P) use this sigma.
__global__ __launch_bounds__(256) void vtrans2(const f16* __restrict__ QKV, f16* __restrict__ VT2) {
  __shared__ alignas(16) f16 tile[64 * 128];  // [kv][d], 16B-chunk XOR-swizzled
  int t = blockIdx.x, bh = blockIdx.y, b = bh >> 4, h = bh & 15;
  int tid = threadIdx.x, w = tid >> 6, l = tid & 63, lg = l >> 4, ln = l & 15;
  const f16* src = QKV + (size_t)(b * S_ + t * 64) * QKV_ST + 4096 + h * HD_;
#pragma unroll
  for (int i = 0; i < 4; i++) {
    int idx = i * 256 + tid;            // 16B-unit index
    int r = idx >> 4, c8 = idx & 15;
    int c8s = c8 ^ ((r >> 3) & 3);      // swizzle: both sides use same XOR
    *(f16x8*)(&tile[r * 128 + c8s * 8]) = *(const f16x8*)(src + (size_t)r * QKV_ST + c8 * 8);
  }
  __syncthreads();
  f16* dst = VT2 + (size_t)(bh * 32 + t) * 16 * 512;
#pragma unroll
  for (int ci = 0; ci < 4; ci++) {
    int c = w * 4 + ci;                 // chunk = nj*2 + kk
    int nj = c >> 1, kk = c & 1;
    f16x8 v;
#pragma unroll
    for (int e = 0; e < 8; e++) {
      int r = 16 * (2 * kk + (e >> 2)) + 4 * lg + (e & 3);  // sigma(k-slot)
      int col = nj * 16 + ln;
      int c8s = (col >> 3) ^ ((r >> 3) & 3);
      v[e] = tile[r * 128 + c8s * 8 + (col & 7)];
    }
    *(f16x8*)(dst + (size_t)c * 512 + l * 8) = v;
  }
}

// flash attention, causal. 8 waves x 16 q-rows (QBLK=128), KV tile = 64,
// TWO KV-TILES PER BARRIER PERIOD: kls[2][2][64*128] (64KB, 2 blocks/CU).
// R11 config (best measured attn, 127.4us). SWAPPED QK^T; lane-local
// softmax; ZERO-SHUFFLE PV (VT2 sigma); Q-RoPE fused into Q load; V
// chunks 0-7 after QK^T; UNIFORM blocks via causal pairing (15-u, u).
// Q/K read from fused qkv (stride 6144); O written back into Q columns.
// lsum quad-reduce deferred to epilogue. log2 scores; T13 defer-max THR=8.
__global__ __launch_bounds__(512, 4) void attn(f16* __restrict__ QKV, const f16* __restrict__ VT2,
                                               const float2* __restrict__ tab) {
  __shared__ alignas(16) f16 kls[2][2][64 * 128];
  int id = blockIdx.x;                   // 512 blocks
  int r8 = id & 7, j = id >> 3;          // j: 0..63 per XCD-residue
  int u = j & 7, g = j >> 3;             // u: pair id, g: bh group 0..7
  int bh = r8 + (g << 3);                // 8 bh's per XCD residue, bh-major
  int b = bh >> 4, h = bh & 15;
  int tid = threadIdx.x, w = tid >> 6, l = tid & 63, lg = l >> 4, ln = l & 15;

  const float QSCALE = 0.12751744910173355f;  // log2(e)/sqrt(128)
  const f16* kp = QKV + (size_t)(b * S_) * QKV_ST + 2048 + h * HD_;
  const f16* vp2 = VT2 + (size_t)bh * 32 * 16 * 512;

  auto stageK = [&](int buf, int half, int kv0) {
#pragma unroll
    for (int jj = 0; jj < 2; jj++) {
      int i = jj * 8 + w;
      int byte = i * 1024 + 16 * l;
      int r = byte >> 8;                       // row 0..63
      int c = (((byte >> 4) & 15) - r) & 15;   // inverse additive swizzle
      gl_lds16(kp + (size_t)(kv0 + r) * QKV_ST + c * 8, (char*)kls[buf][half] + i * 1024);
    }
  };

#pragma unroll 1
  for (int pi = 0; pi < 2; pi++) {
    int qsel = pi ? u : 15 - u;          // heavy pass first (K range in L2)
    int q0 = qsel << 7;
    int qrow = q0 + w * 16 + ln;         // this lane's q row (output column)
    f16* qp = QKV + (size_t)(b * S_ + qrow) * QKV_ST + h * HD_;
    const float2* tq = tab + (size_t)qrow * 64;
    f16x8 qf[4];
#pragma unroll
    for (int kc = 0; kc < 4; kc++) {
      f16x8 q = *(const f16x8*)(qp + kc * 32 + lg * 8);
#pragma unroll
      for (int p = 0; p < 4; p++) {
        float2 cs = tq[kc * 16 + lg * 4 + p];
        float e0 = (float)q[2 * p], e1 = (float)q[2 * p + 1];
        q[2 * p] = (f16)((e0 * cs.x - e1 * cs.y) * QSCALE);
        q[2 * p + 1] = (f16)((e0 * cs.y + e1 * cs.x) * QSCALE);
      }
      qf[kc] = q;
    }

    float m = -1e30f, lsum = 0.f;        // lsum: LANE-LOCAL partial
    f32x4 oacc[8] = {};                  // O^T[d = nj*16 + lg*4 + r4][q = ln]

    int np = qsel + 1;                   // periods; nt64 = 2*qsel+2 tiles
    int nt64 = 2 * qsel + 2;
    if (pi) __syncthreads();             // kls readers from prev pass done
    stageK(0, 0, 0);                     // prologue: period 0 (tiles 0,1)
    stageK(0, 1, 64);
#pragma unroll 1
    for (int p = 0; p < np; p++) {
      __syncthreads();  // drains period-p staging; all waves done with buf
      if (p + 1 < np) {
        stageK((p + 1) & 1, 0, (2 * p + 2) << 6);
        stageK((p + 1) & 1, 1, (2 * p + 3) << 6);
      }
#pragma unroll 1
      for (int ii = 0; ii < 2; ii++) {
        int t = 2 * p + ii;
        int kv0 = t << 6;
        // wave-uniform skip: this wave's rows all precede the tile
        if (kv0 > q0 + w * 16 + 15) continue;
        const f16* kb = kls[p & 1][ii];
        const f16* vt = vp2 + (size_t)t * 16 * 512;

        // S^T = K Q^T: sf[ni][r4] = S[kv = kv0 + ni*16 + lg*4 + r4][q = ln]
        f32x4 sf[4];
        __builtin_amdgcn_s_setprio(1);
#pragma unroll
        for (int ni = 0; ni < 4; ni++) {
          int n = ni * 16 + ln;
          f32x4 s = {0.f, 0.f, 0.f, 0.f};
#pragma unroll
          for (int kc = 0; kc < 4; kc++) {
            int mch = kc * 4 + lg;
            f16x8 kf = *(const f16x8*)(&kb[n * 128 + (((mch + n) & 15) << 3)]);
            s = __builtin_amdgcn_mfma_f32_16x16x32_f16(kf, qf[kc], s, 0, 0, 0);
          }
          sf[ni] = s;
        }
        __builtin_amdgcn_s_setprio(0);

        // V chunks 0-7 issued now; latency hides under mask+softmax
        f16x8 vfa[8];
#pragma unroll
        for (int c = 0; c < 8; c++) vfa[c] = *(const f16x8*)(vt + c * 512 + l * 8);

        if (t >= nt64 - 2) {  // only the two diagonal-adjacent tiles mask
#pragma unroll
          for (int ni = 0; ni < 4; ni++) {
            int kvg = kv0 + ni * 16 + lg * 4;
#pragma unroll
            for (int r4 = 0; r4 < 4; r4++)
              if (kvg + r4 > qrow) sf[ni][r4] = -1e30f;
          }
        }
        // online softmax (log2 domain), lane-local + 2 shfl (max only)
        float pm = fmaxf(fmaxf(fmaxf(sf[0][0], sf[0][1]), fmaxf(sf[0][2], sf[0][3])),
                         fmaxf(fmaxf(sf[1][0], sf[1][1]), fmaxf(sf[1][2], sf[1][3])));
        pm = fmaxf(pm, fmaxf(fmaxf(fmaxf(sf[2][0], sf[2][1]), fmaxf(sf[2][2], sf[2][3])),
                             fmaxf(fmaxf(sf[3][0], sf[3][1]), fmaxf(sf[3][2], sf[3][3]))));
        pm = fmaxf(pm, __shfl_xor(pm, 16));
        pm = fmaxf(pm, __shfl_xor(pm, 32));
        // T13 defer-max: keep old m while tile max hasn't outgrown it by >8
        float scl = 1.f;
        bool defer = __all(pm <= m + 8.f);
        if (!defer) {
          float mn = fmaxf(m, pm);
          scl = __builtin_amdgcn_exp2f(m - mn);
          m = mn;
        }
        float rsum = 0.f;
#pragma unroll
        for (int ni = 0; ni < 4; ni++)
#pragma unroll
          for (int r4 = 0; r4 < 4; r4++) {
            float pv = __builtin_amdgcn_exp2f(sf[ni][r4] - m);
            sf[ni][r4] = pv;
            rsum += pv;
          }
        lsum = lsum * scl + rsum;  // lane-local; cross-lane in epilogue

        // rescale O^T (skipped on defer tiles)
        if (!defer) {
#pragma unroll
          for (int nj = 0; nj < 8; nj++)
#pragma unroll
            for (int r4 = 0; r4 < 4; r4++) oacc[nj][r4] *= scl;
        }

        // ZERO-SHUFFLE pack: pa[kk] = [sf[2kk][0..3], sf[2kk+1][0..3]]
        f16x8 pa[2];
#pragma unroll
        for (int kk = 0; kk < 2; kk++) {
          i32x4 wv;
          wv.x = cvt_pk_i32(sf[2 * kk][0], sf[2 * kk][1]);
          wv.y = cvt_pk_i32(sf[2 * kk][2], sf[2 * kk][3]);
          wv.z = cvt_pk_i32(sf[2 * kk + 1][0], sf[2 * kk + 1][1]);
          wv.w = cvt_pk_i32(sf[2 * kk + 1][2], sf[2 * kk + 1][3]);
          pa[kk] = __builtin_bit_cast(f16x8, wv);
        }

        __builtin_amdgcn_s_setprio(1);
        // PV first half: nj 0-3 from pre-issued vfa (chunk = nj*2+kk)
#pragma unroll
        for (int kk = 0; kk < 2; kk++)
#pragma unroll
          for (int nj = 0; nj < 4; nj++)
            oacc[nj] = __builtin_amdgcn_mfma_f32_16x16x32_f16(vfa[nj * 2 + kk], pa[kk], oacc[nj], 0, 0, 0);
        // PV second half: nj 4-7, in-loop batches of 4
#pragma unroll
        for (int njb = 0; njb < 2; njb++) {
          f16x8 vf[4];
#pragma unroll
          for (int jj = 0; jj < 2; jj++)
#pragma unroll
            for (int kk = 0; kk < 2; kk++)
              vf[jj * 2 + kk] = *(const f16x8*)(vt + (size_t)(((4 + njb * 2 + jj) * 2 + kk) * 512) + l * 8);
#pragma unroll
          for (int kk = 0; kk < 2; kk++)
#pragma unroll
            for (int jj = 0; jj < 2; jj++)
              oacc[4 + njb * 2 + jj] = __builtin_amdgcn_mfma_f32_16x16x32_f16(
                  vf[jj * 2 + kk], pa[kk], oacc[4 + njb * 2 + jj], 0, 0, 0);
        }
        __builtin_amdgcn_s_setprio(0);
      }
    }

    // per-pass epilogue: quad-reduce lane-local lsum; write O into the Q
    // columns of qkv (this block's own rows, already consumed).
    lsum += __shfl_xor(lsum, 16);
    lsum += __shfl_xor(lsum, 32);
    float inv = 1.f / lsum;
#pragma unroll
    for (int nj = 0; nj < 8; nj++) {
      f16x4v ov;
#pragma unroll
      for (int r4 = 0; r4 < 4; r4++) ov[r4] = (f16)(oacc[nj][r4] * inv);
      *(f16x4v*)(qp + nj * 16 + lg * 4) = ov;
    }
  }
}

extern "C" void kernel_launch(void* const* d_in, const int* in_sizes, int n_in,
                              void* d_out, int out_size, void* d_ws, size_t ws_size,
                              hipStream_t stream) {
  (void)in_sizes; (void)n_in; (void)out_size; (void)ws_size;
  const float* x = (const float*)d_in[0];
  // d_in[1] = mask (causal, reproduced analytically)
  const float* Wq = (const float*)d_in[2];
  const float* Wk = (const float*)d_in[3];
  const float* Wv = (const float*)d_in[4];
  const float* Wo = (const float*)d_in[5];
  const int* stp = (const int*)d_in[6];
  float* out = (float*)d_out;

  const size_t MS = (size_t)B_ * S_;  // 8192
  f16* xh = (f16*)d_ws;                         // 32MB
  f16* wqt = xh + MS * D_;                      // wqt|wkt|wvt|wot contiguous, 32MB
  f16* wot = wqt + (size_t)3 * D_ * D_;
  f16* qkv = wot + (size_t)D_ * D_;             // 8192 x 6144 f16, ~100MB
  float2* tab = (float2*)(qkv + MS * (size_t)QKV_ST);
  f16* vt2 = xh;  // reuse: x consumed after the QKV GEMMs

  cvt_f32_to_f16<<<16384, 256, 0, stream>>>(x, xh, (long)(MS * D_));
  wtrans4<<<dim3(4096, 4), 256, 0, stream>>>(Wq, Wk, Wv, Wo, wqt);
  // ONE 768-block launch = 3 subgroup GEMMs (Q,K,V) sharing A in L2.
  gemm8<f16><<<768, 512, 0, stream>>>(xh, wqt, qkv, 8192, 2048, 2048, 2048, QKV_ST,
                                      (long)D_ * D_, 2048);
  rope_table<<<512, 256, 0, stream>>>(tab, stp);
  // K roped in place (qkv cols 2048-4095); Q-RoPE fused into attn.
  rope_apply_k<<<4096, 256, 0, stream>>>(qkv, tab, (long)(MS * 1024));
  vtrans2<<<dim3(32, 64), 256, 0, stream>>>(qkv, vt2);
  // attn reads Q/K from qkv, writes O into qkv's Q columns
  attn<<<512, 512, 0, stream>>>(qkv, vt2, tab);
  // Wo GEMM: A = qkv Q-columns (lda=6144)
  gemm8<float><<<256, 512, 0, stream>>>(qkv, wot, out, 8192, 2048, 2048, QKV_ST, 2048, 0, 0);
}

// Round 15
// 436.788 us; speedup vs baseline: 1.0738x; 1.0345x over previous
//
#include <hip/hip_runtime.h>
#include <hip/hip_fp16.h>

typedef _Float16 f16;
typedef __attribute__((ext_vector_type(2))) _Float16 f16x2;
typedef __attribute__((ext_vector_type(4))) _Float16 f16x4v;
typedef __attribute__((ext_vector_type(8))) _Float16 f16x8;
typedef __attribute__((ext_vector_type(4))) float f32x4;
typedef __attribute__((ext_vector_type(4))) int i32x4;

#define DEV __device__ __forceinline__

static constexpr int S_ = 2048;
static constexpr int D_ = 2048;
static constexpr int H_ = 16;
static constexpr int HD_ = 128;
static constexpr int B_ = 4;
static constexpr int QKV_ST = 6144;  // fused qkv row stride (Q|K|V)

typedef const __attribute__((address_space(1))) void* gptr_t;
typedef __attribute__((address_space(3))) void* lptr_t;

// async global->LDS, 16B per lane. LDS dest must be wave-uniform; HW writes
// dest + lane*16 (m104 semantics). Compiler manages m0.
DEV void gl_lds16(const void* gsrc, void* lds) {
  __builtin_amdgcn_global_load_lds((gptr_t)gsrc, (lptr_t)lds, 16, 0, 0);
}

// f32 pair -> packed f16x2 bits (v_cvt_pkrtz_f16_f32)
DEV int cvt_pk_i32(float a, float b) {
  return __builtin_bit_cast(int, __builtin_amdgcn_cvt_pkrtz(a, b));
}

__global__ __launch_bounds__(256) void cvt_f32_to_f16(const float* __restrict__ in,
                                                      f16* __restrict__ out, long n) {
  long i0 = ((long)blockIdx.x * 256 + threadIdx.x) * 4;
  long stride = (long)gridDim.x * 256 * 4;
  for (long i = i0; i < n; i += stride) {
    float4 v = *(const float4*)(in + i);
    f16x4v o;
    o[0] = (f16)v.x; o[1] = (f16)v.y; o[2] = (f16)v.z; o[3] = (f16)v.w;
    *(f16x4v*)(out + i) = o;
  }
}

// W (2048 x 2048, row-major K x N) -> Wt (N x K) fp16; 4 weights, one launch.
__global__ __launch_bounds__(256) void wtrans4(const float* __restrict__ W0, const float* __restrict__ W1,
                                               const float* __restrict__ W2, const float* __restrict__ W3,
                                               f16* __restrict__ Wt) {
  __shared__ float tile[32][33];
  int wi = blockIdx.y;
  const float* W = wi == 0 ? W0 : wi == 1 ? W1 : wi == 2 ? W2 : W3;
  f16* dst = Wt + (size_t)wi * D_ * D_;
  int bx = blockIdx.x & 63, by = blockIdx.x >> 6;
  int r0 = by << 5, c0 = bx << 5;
  int tx = threadIdx.x & 31, ty = threadIdx.x >> 5;
#pragma unroll
  for (int i = 0; i < 4; i++) {
    int r = ty + i * 8;
    tile[r][tx] = W[(size_t)(r0 + r) * D_ + c0 + tx];
  }
  __syncthreads();
#pragma unroll
  for (int i = 0; i < 4; i++) {
    int r = ty + i * 8;
    dst[(size_t)(c0 + r) * D_ + r0 + tx] = (f16)tile[tx][r];
  }
}

// swizzled LDS fragment read: [128][64] f16 half-tile, full 3-bit XOR
// swizzle (R14: conflicts measured 0): group = (s*4+lg)^(ln&7).
DEV f16x8 lds_frag(const f16* half, int row, int s, int lg) {
  int byte = row * 128 + s * 64 + lg * 16;
  byte ^= (row & 7) << 4;
  return *(const f16x8*)((const char*)half + byte);
}

// C = A(MxK, row stride lda) * Bt(NxK)^T ; C row stride ldc. 256x256 tile,
// BK=64, 8 waves, 512 thr. Multi-subgroup fusion: subgroup = bid/nwg picks
// B/C offsets (QKV GEMMs share A in one grid).
// TWO-PHASE K-loop (R14 fix): the old 4-phase/9-barrier tile lockstepped
// all 8 waves around ~80-cycle MFMA windows -- fixed barrier cost ate the
// phase (MfmaUtil 39%, conflicts 0, HBM 8%: nothing saturated = m97-style
// sync-bound). Now per tile: entry(vmcnt4+bar) -> [16 ds_read (b0,b1,
// a-k0 both halves) + stage A(t+1)] -> 32 MFMA(k0) -> bar -> [8 ds_read
// (a-k1) + stage B(t+2)] -> 32 MFMA(k1) -> next entry. 2 barriers/tile.
// Hazards: entry bar orders gl_lds16 writes vs reads (per-wave vmcnt +
// collective barrier); mid bar orders all waves' b0/b1 reads (lgkmcnt-
// complete before their k0 MFMA, hence before arrival) vs the B(t+2)
// overwrite of Bs[t&1]; trailing bar is redundant with next entry bar
// (a-k1 reads complete before k1 MFMA issue, before arrival).
template <typename CT>
__global__ __launch_bounds__(512, 2) void gemm8(const f16* __restrict__ A, const f16* __restrict__ Bt,
                                                CT* __restrict__ C, int M, int N, int K,
                                                int lda, int ldc, long subB, long subC) {
  __shared__ alignas(16) f16 As[2][2][128 * 64];
  __shared__ alignas(16) f16 Bs[2][2][128 * 64];
  int nbx = N >> 8;
  int nwg = (M >> 8) * nbx;  // per-subgroup wg count (%8==0; ours: 256)
  int bid = blockIdx.x;
  int wi = bid / nwg;                            // subgroup (0 if plain)
  int bidl = bid - wi * nwg;
  Bt += (size_t)wi * subB;
  C += (size_t)wi * subC;
  int wg = (bidl & 7) * (nwg >> 3) + (bidl >> 3);  // XCD-contiguous chunks
  int bx = wg % nbx, by = wg / nbx;
  int tid = threadIdx.x, w = tid >> 6, l = tid & 63;
  int wm = w >> 2, wn = w & 3, lg = l >> 4, ln = l & 15;
  int nt = K >> 6;
  const f16* Ab = A + (size_t)(by * 256) * lda;
  const f16* Bb = Bt + (size_t)(bx * 256) * K;

  // stage one [128][64] half-tile: linear LDS dest (gl_lds16 requirement),
  // source slot = (l&7) ^ (row&7) -- same involution as lds_frag (rule #21).
  auto stageA = [&](const f16* src0, int kt, f16* dst) {
#pragma unroll
    for (int j = 0; j < 2; j++) {
      int c = j * 8 + w;                       // 1KB chunk
      int row = c * 8 + (l >> 3);
      int scol = ((l & 7) ^ (row & 7)) << 3;   // elems (16B units)
      gl_lds16(src0 + (size_t)row * lda + kt * 64 + scol, (char*)dst + c * 1024);
    }
  };
  auto stageB = [&](const f16* src0, int kt, f16* dst) {
#pragma unroll
    for (int j = 0; j < 2; j++) {
      int c = j * 8 + w;                       // 1KB chunk
      int row = c * 8 + (l >> 3);
      int scol = ((l & 7) ^ (row & 7)) << 3;
      gl_lds16(src0 + (size_t)row * K + kt * 64 + scol, (char*)dst + c * 1024);
    }
  };

  f32x4 acc[8][4] = {};

  // prologue: tile0 A+B, tile1 B
  stageA(Ab, 0, As[0][0]);
  stageA(Ab + (size_t)128 * lda, 0, As[0][1]);
  stageB(Bb, 0, Bs[0][0]);
  stageB(Bb + (size_t)128 * K, 0, Bs[0][1]);
  if (nt > 1) {
    stageB(Bb, 1, Bs[1][0]);
    stageB(Bb + (size_t)128 * K, 1, Bs[1][1]);
  }

  for (int t = 0; t < nt; t++) {
    // tile-entry drain: A(t)+B(t) landed for every wave, collective barrier
    if (t + 2 < nt) asm volatile("s_waitcnt vmcnt(4)" ::: "memory");
    else            asm volatile("s_waitcnt vmcnt(0)" ::: "memory");
    __builtin_amdgcn_s_barrier();
    asm volatile("" ::: "memory");
    const f16* Ah = As[t & 1][wm];
    const f16* Bh = Bs[t & 1][wn >> 1];
    int br0 = (wn & 1) * 64;
    f16x8 alo[4], ahi[4], b0[4], b1[4];
    // ---- pA: all B fragments (k0,k1) + A k0 (both row-halves); stage A(t+1)
#pragma unroll
    for (int i = 0; i < 4; i++) b0[i] = lds_frag(Bh, br0 + i * 16 + ln, 0, lg);
#pragma unroll
    for (int i = 0; i < 4; i++) b1[i] = lds_frag(Bh, br0 + i * 16 + ln, 1, lg);
#pragma unroll
    for (int i = 0; i < 4; i++) alo[i] = lds_frag(Ah, i * 16 + ln, 0, lg);
#pragma unroll
    for (int i = 0; i < 4; i++) ahi[i] = lds_frag(Ah, 64 + i * 16 + ln, 0, lg);
    if (t + 1 < nt) {
      stageA(Ab, t + 1, As[(t + 1) & 1][0]);
      stageA(Ab + (size_t)128 * lda, t + 1, As[(t + 1) & 1][1]);
    }
    __builtin_amdgcn_s_setprio(1);
#pragma unroll
    for (int mi = 0; mi < 4; mi++)
#pragma unroll
      for (int ni = 0; ni < 4; ni++) {
        acc[mi][ni] = __builtin_amdgcn_mfma_f32_16x16x32_f16(alo[mi], b0[ni], acc[mi][ni], 0, 0, 0);
        acc[mi + 4][ni] = __builtin_amdgcn_mfma_f32_16x16x32_f16(ahi[mi], b0[ni], acc[mi + 4][ni], 0, 0, 0);
      }
    __builtin_amdgcn_s_setprio(0);
    // mid barrier: all waves' b0/b1 reads completed (lgkmcnt precedes their
    // k0 MFMA) -> safe to overwrite Bs[t&1] with B(t+2) below.
    __builtin_amdgcn_s_barrier();
    asm volatile("" ::: "memory");
    // ---- pB: A k1 (both halves); stage B(t+2) into the freed Bs[t&1]
#pragma unroll
    for (int i = 0; i < 4; i++) alo[i] = lds_frag(Ah, i * 16 + ln, 1, lg);
#pragma unroll
    for (int i = 0; i < 4; i++) ahi[i] = lds_frag(Ah, 64 + i * 16 + ln, 1, lg);
    if (t + 2 < nt) {
      stageB(Bb, t + 2, Bs[t & 1][0]);
      stageB(Bb + (size_t)128 * K, t + 2, Bs[t & 1][1]);
    }
    __builtin_amdgcn_s_setprio(1);
#pragma unroll
    for (int mi = 0; mi < 4; mi++)
#pragma unroll
      for (int ni = 0; ni < 4; ni++) {
        acc[mi][ni] = __builtin_amdgcn_mfma_f32_16x16x32_f16(alo[mi], b1[ni], acc[mi][ni], 0, 0, 0);
        acc[mi + 4][ni] = __builtin_amdgcn_mfma_f32_16x16x32_f16(ahi[mi], b1[ni], acc[mi + 4][ni], 0, 0, 0);
      }
    __builtin_amdgcn_s_setprio(0);
    asm volatile("" ::: "memory");
    // no trailing barrier: next tile's entry barrier suffices (a-k1 reads
    // complete before each wave's k1 MFMA issue, hence before arrival).
  }

  int row0 = by * 256 + wm * 128;
  int col0 = bx * 256 + wn * 64;
#pragma unroll
  for (int mi = 0; mi < 8; mi++)
#pragma unroll
    for (int ni = 0; ni < 4; ni++)
#pragma unroll
      for (int r4 = 0; r4 < 4; r4++) {
        int row = row0 + mi * 16 + lg * 4 + r4;
        int col = col0 + ni * 16 + ln;
        float o = acc[mi][ni][r4];
        if constexpr (sizeof(CT) == 2) {
          float oo = __shfl_xor(o, 1);
          if (!(ln & 1)) {
            f16x2 pp; pp[0] = (f16)o; pp[1] = (f16)oo;
            *(f16x2*)(&C[(size_t)row * ldc + col]) = pp;
          }
        } else {
          C[(size_t)row * ldc + col] = o;
        }
      }
}

__global__ __launch_bounds__(256) void rope_table(float2* __restrict__ tab, const int* __restrict__ st) {
  int i = blockIdx.x * 256 + threadIdx.x;  // S*64 entries
  int s = i >> 6, j = i & 63;
  float theta = powf(10000.f, -(float)j / 64.f);
  float ang = (float)(s + st[0]) * theta;
  tab[i] = make_float2(cosf(ang), sinf(ang));
}

// RoPE over the K columns (2048..4095) of the fused qkv buffer, in place.
__global__ __launch_bounds__(256) void rope_apply_k(f16* __restrict__ QKV, const float2* __restrict__ tab,
                                                    long npairs) {
  long i0 = (long)blockIdx.x * 256 + threadIdx.x;
  long stride = (long)gridDim.x * 256;
  for (long p = i0; p < npairs; p += stride) {
    long row = p >> 10;            // 1024 K-pairs per row
    int jp = (int)(p & 1023);
    int s = (int)(row & (S_ - 1));
    float2 cs = tab[s * 64 + (jp & 63)];
    f16* px = QKV + row * QKV_ST + 2048 + 2 * jp;
    f16x2 v = *(const f16x2*)px;
    float xe = (float)v[0], xo = (float)v[1];
    float re = xe * cs.x - xo * cs.y;
    float ro = xe * cs.y + xo * cs.x;
    f16x2 o; o[0] = (f16)re; o[1] = (f16)ro;
    *(f16x2*)px = o;
  }
}

// V (qkv cols 4096+) -> VT2 fragment-linear with the ZERO-SHUFFLE k<->kv
// mapping: per (bh, kv-tile t, nj, kk) one 1KB chunk; lane l=(lg*16+ln),
// element e owns V[d = nj*16 + ln][kv = t*64 + 16*(2kk+(e>>2)) + 4lg + (e&3)].
// Sigma matches QK^T's lane-local layout so attn's PV B-operand is a pure
// in-register pack. Both A (V) and B (P) use this sigma.
__global__ __launch_bounds__(256) void vtrans2(const f16* __restrict__ QKV, f16* __restrict__ VT2) {
  __shared__ alignas(16) f16 tile[64 * 128];  // [kv][d], 16B-chunk XOR-swizzled
  int t = blockIdx.x, bh = blockIdx.y, b = bh >> 4, h = bh & 15;
  int tid = threadIdx.x, w = tid >> 6, l = tid & 63, lg = l >> 4, ln = l & 15;
  const f16* src = QKV + (size_t)(b * S_ + t * 64) * QKV_ST + 4096 + h * HD_;
#pragma unroll
  for (int i = 0; i < 4; i++) {
    int idx = i * 256 + tid;            // 16B-unit index
    int r = idx >> 4, c8 = idx & 15;
    int c8s = c8 ^ ((r >> 3) & 3);      // swizzle: both sides use same XOR
    *(f16x8*)(&tile[r * 128 + c8s * 8]) = *(const f16x8*)(src + (size_t)r * QKV_ST + c8 * 8);
  }
  __syncthreads();
  f16* dst = VT2 + (size_t)(bh * 32 + t) * 16 * 512;
#pragma unroll
  for (int ci = 0; ci < 4; ci++) {
    int c = w * 4 + ci;                 // chunk = nj*2 + kk
    int nj = c >> 1, kk = c & 1;
    f16x8 v;
#pragma unroll
    for (int e = 0; e < 8; e++) {
      int r = 16 * (2 * kk + (e >> 2)) + 4 * lg + (e & 3);  // sigma(k-slot)
      int col = nj * 16 + ln;
      int c8s = (col >> 3) ^ ((r >> 3) & 3);
      v[e] = tile[r * 128 + c8s * 8 + (col & 7)];
    }
    *(f16x8*)(dst + (size_t)c * 512 + l * 8) = v;
  }
}

// flash attention, causal. 8 waves x 16 q-rows (QBLK=128), KV tile = 64,
// TWO KV-TILES PER BARRIER PERIOD: kls[2][2][64*128] (64KB, 2 blocks/CU).
// R11 config (best measured attn, 127.4us). SWAPPED QK^T; lane-local
// softmax; ZERO-SHUFFLE PV (VT2 sigma); Q-RoPE fused into Q load; V
// chunks 0-7 after QK^T; UNIFORM blocks via causal pairing (15-u, u).
// Q/K read from fused qkv (stride 6144); O written back into Q columns.
// lsum quad-reduce deferred to epilogue. log2 scores; T13 defer-max THR=8.
__global__ __launch_bounds__(512, 4) void attn(f16* __restrict__ QKV, const f16* __restrict__ VT2,
                                               const float2* __restrict__ tab) {
  __shared__ alignas(16) f16 kls[2][2][64 * 128];
  int id = blockIdx.x;                   // 512 blocks
  int r8 = id & 7, j = id >> 3;          // j: 0..63 per XCD-residue
  int u = j & 7, g = j >> 3;             // u: pair id, g: bh group 0..7
  int bh = r8 + (g << 3);                // 8 bh's per XCD residue, bh-major
  int b = bh >> 4, h = bh & 15;
  int tid = threadIdx.x, w = tid >> 6, l = tid & 63, lg = l >> 4, ln = l & 15;

  const float QSCALE = 0.12751744910173355f;  // log2(e)/sqrt(128)
  const f16* kp = QKV + (size_t)(b * S_) * QKV_ST + 2048 + h * HD_;
  const f16* vp2 = VT2 + (size_t)bh * 32 * 16 * 512;

  auto stageK = [&](int buf, int half, int kv0) {
#pragma unroll
    for (int jj = 0; jj < 2; jj++) {
      int i = jj * 8 + w;
      int byte = i * 1024 + 16 * l;
      int r = byte >> 8;                       // row 0..63
      int c = (((byte >> 4) & 15) - r) & 15;   // inverse additive swizzle
      gl_lds16(kp + (size_t)(kv0 + r) * QKV_ST + c * 8, (char*)kls[buf][half] + i * 1024);
    }
  };

#pragma unroll 1
  for (int pi = 0; pi < 2; pi++) {
    int qsel = pi ? u : 15 - u;          // heavy pass first (K range in L2)
    int q0 = qsel << 7;
    int qrow = q0 + w * 16 + ln;         // this lane's q row (output column)
    f16* qp = QKV + (size_t)(b * S_ + qrow) * QKV_ST + h * HD_;
    const float2* tq = tab + (size_t)qrow * 64;
    f16x8 qf[4];
#pragma unroll
    for (int kc = 0; kc < 4; kc++) {
      f16x8 q = *(const f16x8*)(qp + kc * 32 + lg * 8);
#pragma unroll
      for (int p = 0; p < 4; p++) {
        float2 cs = tq[kc * 16 + lg * 4 + p];
        float e0 = (float)q[2 * p], e1 = (float)q[2 * p + 1];
        q[2 * p] = (f16)((e0 * cs.x - e1 * cs.y) * QSCALE);
        q[2 * p + 1] = (f16)((e0 * cs.y + e1 * cs.x) * QSCALE);
      }
      qf[kc] = q;
    }

    float m = -1e30f, lsum = 0.f;        // lsum: LANE-LOCAL partial
    f32x4 oacc[8] = {};                  // O^T[d = nj*16 + lg*4 + r4][q = ln]

    int np = qsel + 1;                   // periods; nt64 = 2*qsel+2 tiles
    int nt64 = 2 * qsel + 2;
    if (pi) __syncthreads();             // kls readers from prev pass done
    stageK(0, 0, 0);                     // prologue: period 0 (tiles 0,1)
    stageK(0, 1, 64);
#pragma unroll 1
    for (int p = 0; p < np; p++) {
      __syncthreads();  // drains period-p staging; all waves done with buf
      if (p + 1 < np) {
        stageK((p + 1) & 1, 0, (2 * p + 2) << 6);
        stageK((p + 1) & 1, 1, (2 * p + 3) << 6);
      }
#pragma unroll 1
      for (int ii = 0; ii < 2; ii++) {
        int t = 2 * p + ii;
        int kv0 = t << 6;
        // wave-uniform skip: this wave's rows all precede the tile
        if (kv0 > q0 + w * 16 + 15) continue;
        const f16* kb = kls[p & 1][ii];
        const f16* vt = vp2 + (size_t)t * 16 * 512;

        // S^T = K Q^T: sf[ni][r4] = S[kv = kv0 + ni*16 + lg*4 + r4][q = ln]
        f32x4 sf[4];
        __builtin_amdgcn_s_setprio(1);
#pragma unroll
        for (int ni = 0; ni < 4; ni++) {
          int n = ni * 16 + ln;
          f32x4 s = {0.f, 0.f, 0.f, 0.f};
#pragma unroll
          for (int kc = 0; kc < 4; kc++) {
            int mch = kc * 4 + lg;
            f16x8 kf = *(const f16x8*)(&kb[n * 128 + (((mch + n) & 15) << 3)]);
            s = __builtin_amdgcn_mfma_f32_16x16x32_f16(kf, qf[kc], s, 0, 0, 0);
          }
          sf[ni] = s;
        }
        __builtin_amdgcn_s_setprio(0);

        // V chunks 0-7 issued now; latency hides under mask+softmax
        f16x8 vfa[8];
#pragma unroll
        for (int c = 0; c < 8; c++) vfa[c] = *(const f16x8*)(vt + c * 512 + l * 8);

        if (t >= nt64 - 2) {  // only the two diagonal-adjacent tiles mask
#pragma unroll
          for (int ni = 0; ni < 4; ni++) {
            int kvg = kv0 + ni * 16 + lg * 4;
#pragma unroll
            for (int r4 = 0; r4 < 4; r4++)
              if (kvg + r4 > qrow) sf[ni][r4] = -1e30f;
          }
        }
        // online softmax (log2 domain), lane-local + 2 shfl (max only)
        float pm = fmaxf(fmaxf(fmaxf(sf[0][0], sf[0][1]), fmaxf(sf[0][2], sf[0][3])),
                         fmaxf(fmaxf(sf[1][0], sf[1][1]), fmaxf(sf[1][2], sf[1][3])));
        pm = fmaxf(pm, fmaxf(fmaxf(fmaxf(sf[2][0], sf[2][1]), fmaxf(sf[2][2], sf[2][3])),
                             fmaxf(fmaxf(sf[3][0], sf[3][1]), fmaxf(sf[3][2], sf[3][3]))));
        pm = fmaxf(pm, __shfl_xor(pm, 16));
        pm = fmaxf(pm, __shfl_xor(pm, 32));
        // T13 defer-max: keep old m while tile max hasn't outgrown it by >8
        float scl = 1.f;
        bool defer = __all(pm <= m + 8.f);
        if (!defer) {
          float mn = fmaxf(m, pm);
          scl = __builtin_amdgcn_exp2f(m - mn);
          m = mn;
        }
        float rsum = 0.f;
#pragma unroll
        for (int ni = 0; ni < 4; ni++)
#pragma unroll
          for (int r4 = 0; r4 < 4; r4++) {
            float pv = __builtin_amdgcn_exp2f(sf[ni][r4] - m);
            sf[ni][r4] = pv;
            rsum += pv;
          }
        lsum = lsum * scl + rsum;  // lane-local; cross-lane in epilogue

        // rescale O^T (skipped on defer tiles)
        if (!defer) {
#pragma unroll
          for (int nj = 0; nj < 8; nj++)
#pragma unroll
            for (int r4 = 0; r4 < 4; r4++) oacc[nj][r4] *= scl;
        }

        // ZERO-SHUFFLE pack: pa[kk] = [sf[2kk][0..3], sf[2kk+1][0..3]]
        f16x8 pa[2];
#pragma unroll
        for (int kk = 0; kk < 2; kk++) {
          i32x4 wv;
          wv.x = cvt_pk_i32(sf[2 * kk][0], sf[2 * kk][1]);
          wv.y = cvt_pk_i32(sf[2 * kk][2], sf[2 * kk][3]);
          wv.z = cvt_pk_i32(sf[2 * kk + 1][0], sf[2 * kk + 1][1]);
          wv.w = cvt_pk_i32(sf[2 * kk + 1][2], sf[2 * kk + 1][3]);
          pa[kk] = __builtin_bit_cast(f16x8, wv);
        }

        __builtin_amdgcn_s_setprio(1);
        // PV first half: nj 0-3 from pre-issued vfa (chunk = nj*2+kk)
#pragma unroll
        for (int kk = 0; kk < 2; kk++)
#pragma unroll
          for (int nj = 0; nj < 4; nj++)
            oacc[nj] = __builtin_amdgcn_mfma_f32_16x16x32_f16(vfa[nj * 2 + kk], pa[kk], oacc[nj], 0, 0, 0);
        // PV second half: nj 4-7, in-loop batches of 4
#pragma unroll
        for (int njb = 0; njb < 2; njb++) {
          f16x8 vf[4];
#pragma unroll
          for (int jj = 0; jj < 2; jj++)
#pragma unroll
            for (int kk = 0; kk < 2; kk++)
              vf[jj * 2 + kk] = *(const f16x8*)(vt + (size_t)(((4 + njb * 2 + jj) * 2 + kk) * 512) + l * 8);
#pragma unroll
          for (int kk = 0; kk < 2; kk++)
#pragma unroll
            for (int jj = 0; jj < 2; jj++)
              oacc[4 + njb * 2 + jj] = __builtin_amdgcn_mfma_f32_16x16x32_f16(
                  vf[jj * 2 + kk], pa[kk], oacc[4 + njb * 2 + jj], 0, 0, 0);
        }
        __builtin_amdgcn_s_setprio(0);
      }
    }

    // per-pass epilogue: quad-reduce lane-local lsum; write O into the Q
    // columns of qkv (this block's own rows, already consumed).
    lsum += __shfl_xor(lsum, 16);
    lsum += __shfl_xor(lsum, 32);
    float inv = 1.f / lsum;
#pragma unroll
    for (int nj = 0; nj < 8; nj++) {
      f16x4v ov;
#pragma unroll
      for (int r4 = 0; r4 < 4; r4++) ov[r4] = (f16)(oacc[nj][r4] * inv);
      *(f16x4v*)(qp + nj * 16 + lg * 4) = ov;
    }
  }
}

extern "C" void kernel_launch(void* const* d_in, const int* in_sizes, int n_in,
                              void* d_out, int out_size, void* d_ws, size_t ws_size,
                              hipStream_t stream) {
  (void)in_sizes; (void)n_in; (void)out_size; (void)ws_size;
  const float* x = (const float*)d_in[0];
  // d_in[1] = mask (causal, reproduced analytically)
  const float* Wq = (const float*)d_in[2];
  const float* Wk = (const float*)d_in[3];
  const float* Wv = (const float*)d_in[4];
  const float* Wo = (const float*)d_in[5];
  const int* stp = (const int*)d_in[6];
  float* out = (float*)d_out;

  const size_t MS = (size_t)B_ * S_;  // 8192
  f16* xh = (f16*)d_ws;                         // 32MB
  f16* wqt = xh + MS * D_;                      // wqt|wkt|wvt|wot contiguous, 32MB
  f16* wot = wqt + (size_t)3 * D_ * D_;
  f16* qkv = wot + (size_t)D_ * D_;             // 8192 x 6144 f16, ~100MB
  float2* tab = (float2*)(qkv + MS * (size_t)QKV_ST);
  f16* vt2 = xh;  // reuse: x consumed after the QKV GEMMs

  cvt_f32_to_f16<<<16384, 256, 0, stream>>>(x, xh, (long)(MS * D_));
  wtrans4<<<dim3(4096, 4), 256, 0, stream>>>(Wq, Wk, Wv, Wo, wqt);
  // ONE 768-block launch = 3 subgroup GEMMs (Q,K,V) sharing A in L2.
  gemm8<f16><<<768, 512, 0, stream>>>(xh, wqt, qkv, 8192, 2048, 2048, 2048, QKV_ST,
                                      (long)D_ * D_, 2048);
  rope_table<<<512, 256, 0, stream>>>(tab, stp);
  // K roped in place (qkv cols 2048-4095); Q-RoPE fused into attn.
  rope_apply_k<<<4096, 256, 0, stream>>>(qkv, tab, (long)(MS * 1024));
  vtrans2<<<dim3(32, 64), 256, 0, stream>>>(qkv, vt2);
  // attn reads Q/K from qkv, writes O into qkv's Q columns
  attn<<<512, 512, 0, stream>>>(qkv, vt2, tab);
  // Wo GEMM: A = qkv Q-columns (lda=6144)
  gemm8<float><<<256, 512, 0, stream>>>(qkv, wot, out, 8192, 2048, 2048, QKV_ST, 2048, 0, 0);
}

// Round 16
// 433.549 us; speedup vs baseline: 1.0818x; 1.0075x over previous
//
#include <hip/hip_runtime.h>
#include <hip/hip_fp16.h>

typedef _Float16 f16;
typedef __attribute__((ext_vector_type(2))) _Float16 f16x2;
typedef __attribute__((ext_vector_type(4))) _Float16 f16x4v;
typedef __attribute__((ext_vector_type(8))) _Float16 f16x8;
typedef __attribute__((ext_vector_type(4))) float f32x4;
typedef __attribute__((ext_vector_type(4))) int i32x4;

#define DEV __device__ __forceinline__

static constexpr int S_ = 2048;
static constexpr int D_ = 2048;
static constexpr int H_ = 16;
static constexpr int HD_ = 128;
static constexpr int B_ = 4;
static constexpr int QKV_ST = 6144;  // fused qkv row stride (Q|K|V)

typedef const __attribute__((address_space(1))) void* gptr_t;
typedef __attribute__((address_space(3))) void* lptr_t;

// async global->LDS, 16B per lane. LDS dest must be wave-uniform; HW writes
// dest + lane*16 (m104 semantics). Compiler manages m0.
DEV void gl_lds16(const void* gsrc, void* lds) {
  __builtin_amdgcn_global_load_lds((gptr_t)gsrc, (lptr_t)lds, 16, 0, 0);
}

// f32 pair -> packed f16x2 bits (v_cvt_pkrtz_f16_f32)
DEV int cvt_pk_i32(float a, float b) {
  return __builtin_bit_cast(int, __builtin_amdgcn_cvt_pkrtz(a, b));
}

__global__ __launch_bounds__(256) void cvt_f32_to_f16(const float* __restrict__ in,
                                                      f16* __restrict__ out, long n) {
  long i0 = ((long)blockIdx.x * 256 + threadIdx.x) * 4;
  long stride = (long)gridDim.x * 256 * 4;
  for (long i = i0; i < n; i += stride) {
    float4 v = *(const float4*)(in + i);
    f16x4v o;
    o[0] = (f16)v.x; o[1] = (f16)v.y; o[2] = (f16)v.z; o[3] = (f16)v.w;
    *(f16x4v*)(out + i) = o;
  }
}

// W (2048 x 2048, row-major K x N) -> Wt (N x K) fp16; 4 weights, one launch.
__global__ __launch_bounds__(256) void wtrans4(const float* __restrict__ W0, const float* __restrict__ W1,
                                               const float* __restrict__ W2, const float* __restrict__ W3,
                                               f16* __restrict__ Wt) {
  __shared__ float tile[32][33];
  int wi = blockIdx.y;
  const float* W = wi == 0 ? W0 : wi == 1 ? W1 : wi == 2 ? W2 : W3;
  f16* dst = Wt + (size_t)wi * D_ * D_;
  int bx = blockIdx.x & 63, by = blockIdx.x >> 6;
  int r0 = by << 5, c0 = bx << 5;
  int tx = threadIdx.x & 31, ty = threadIdx.x >> 5;
#pragma unroll
  for (int i = 0; i < 4; i++) {
    int r = ty + i * 8;
    tile[r][tx] = W[(size_t)(r0 + r) * D_ + c0 + tx];
  }
  __syncthreads();
#pragma unroll
  for (int i = 0; i < 4; i++) {
    int r = ty + i * 8;
    dst[(size_t)(c0 + r) * D_ + r0 + tx] = (f16)tile[tx][r];
  }
}

// swizzled LDS fragment read: [128][64] f16 half-tile, full 3-bit XOR
// swizzle (R14: conflicts measured 0): group = (s*4+lg)^(ln&7).
DEV f16x8 lds_frag(const f16* half, int row, int s, int lg) {
  int byte = row * 128 + s * 64 + lg * 16;
  byte ^= (row & 7) << 4;
  return *(const f16x8*)((const char*)half + byte);
}

// C = A(MxK, row stride lda) * Bt(NxK)^T ; C row stride ldc. 256x256 tile,
// BK=64, 8 waves, 512 thr. Multi-subgroup fusion: subgroup = bid/nwg picks
// B/C offsets (QKV GEMMs share A in one grid).
// ONE-BARRIER K-loop (R15: 9->2 barriers/tile gave 236->217us; finish it).
// Plain 1-ahead dbuf for BOTH operands into the OPPOSITE buffer: the old
// mid-barrier existed only because B was staged 2-ahead into the current
// buffer. Per tile: entry(vmcnt0+bar) -> [16 ds_read b0/b1/a-k0 + stage
// A(t+1),B(t+1) -> bufs [(t+1)&1]] -> 32 MFMA(k0) -> [8 ds_read a-k1, no
// barrier: As[t&1] not overwritten this tile] -> 32 MFMA(k1).
// Safety induction: buffers [(t+1)&1] held tile t-1 data; every wave's
// reads of them completed before its tile t-1 MFMAs, hence before its
// arrival at tile t's entry barrier -- so the stage (issued after that
// barrier) cannot race any read. Entry vmcnt(0) drains the 8 loads issued
// at the START of the previous tile body (>=2000cy slack >> HBM ~900cy).
template <typename CT>
__global__ __launch_bounds__(512, 2) void gemm8(const f16* __restrict__ A, const f16* __restrict__ Bt,
                                                CT* __restrict__ C, int M, int N, int K,
                                                int lda, int ldc, long subB, long subC) {
  __shared__ alignas(16) f16 As[2][2][128 * 64];
  __shared__ alignas(16) f16 Bs[2][2][128 * 64];
  int nbx = N >> 8;
  int nwg = (M >> 8) * nbx;  // per-subgroup wg count (%8==0; ours: 256)
  int bid = blockIdx.x;
  int wi = bid / nwg;                            // subgroup (0 if plain)
  int bidl = bid - wi * nwg;
  Bt += (size_t)wi * subB;
  C += (size_t)wi * subC;
  int wg = (bidl & 7) * (nwg >> 3) + (bidl >> 3);  // XCD-contiguous chunks
  int bx = wg % nbx, by = wg / nbx;
  int tid = threadIdx.x, w = tid >> 6, l = tid & 63;
  int wm = w >> 2, wn = w & 3, lg = l >> 4, ln = l & 15;
  int nt = K >> 6;
  const f16* Ab = A + (size_t)(by * 256) * lda;
  const f16* Bb = Bt + (size_t)(bx * 256) * K;

  // stage one [128][64] half-tile: linear LDS dest (gl_lds16 requirement),
  // source slot = (l&7) ^ (row&7) -- same involution as lds_frag (rule #21).
  auto stageA = [&](const f16* src0, int kt, f16* dst) {
#pragma unroll
    for (int j = 0; j < 2; j++) {
      int c = j * 8 + w;                       // 1KB chunk
      int row = c * 8 + (l >> 3);
      int scol = ((l & 7) ^ (row & 7)) << 3;   // elems (16B units)
      gl_lds16(src0 + (size_t)row * lda + kt * 64 + scol, (char*)dst + c * 1024);
    }
  };
  auto stageB = [&](const f16* src0, int kt, f16* dst) {
#pragma unroll
    for (int j = 0; j < 2; j++) {
      int c = j * 8 + w;                       // 1KB chunk
      int row = c * 8 + (l >> 3);
      int scol = ((l & 7) ^ (row & 7)) << 3;
      gl_lds16(src0 + (size_t)row * K + kt * 64 + scol, (char*)dst + c * 1024);
    }
  };

  f32x4 acc[8][4] = {};

  // prologue: tile0 A+B
  stageA(Ab, 0, As[0][0]);
  stageA(Ab + (size_t)128 * lda, 0, As[0][1]);
  stageB(Bb, 0, Bs[0][0]);
  stageB(Bb + (size_t)128 * K, 0, Bs[0][1]);

  for (int t = 0; t < nt; t++) {
    // tile-entry drain: A(t)+B(t) landed for every wave, collective barrier
    asm volatile("s_waitcnt vmcnt(0)" ::: "memory");
    __builtin_amdgcn_s_barrier();
    asm volatile("" ::: "memory");
    const f16* Ah = As[t & 1][wm];
    const f16* Bh = Bs[t & 1][wn >> 1];
    int br0 = (wn & 1) * 64;
    f16x8 alo[4], ahi[4], b0[4], b1[4];
    // all B fragments (k0,k1) + A k0 (both row-halves)
#pragma unroll
    for (int i = 0; i < 4; i++) b0[i] = lds_frag(Bh, br0 + i * 16 + ln, 0, lg);
#pragma unroll
    for (int i = 0; i < 4; i++) b1[i] = lds_frag(Bh, br0 + i * 16 + ln, 1, lg);
#pragma unroll
    for (int i = 0; i < 4; i++) alo[i] = lds_frag(Ah, i * 16 + ln, 0, lg);
#pragma unroll
    for (int i = 0; i < 4; i++) ahi[i] = lds_frag(Ah, 64 + i * 16 + ln, 0, lg);
    // 1-ahead stage of BOTH operands into the opposite buffers
    if (t + 1 < nt) {
      stageA(Ab, t + 1, As[(t + 1) & 1][0]);
      stageA(Ab + (size_t)128 * lda, t + 1, As[(t + 1) & 1][1]);
      stageB(Bb, t + 1, Bs[(t + 1) & 1][0]);
      stageB(Bb + (size_t)128 * K, t + 1, Bs[(t + 1) & 1][1]);
    }
    __builtin_amdgcn_s_setprio(1);
#pragma unroll
    for (int mi = 0; mi < 4; mi++)
#pragma unroll
      for (int ni = 0; ni < 4; ni++) {
        acc[mi][ni] = __builtin_amdgcn_mfma_f32_16x16x32_f16(alo[mi], b0[ni], acc[mi][ni], 0, 0, 0);
        acc[mi + 4][ni] = __builtin_amdgcn_mfma_f32_16x16x32_f16(ahi[mi], b0[ni], acc[mi + 4][ni], 0, 0, 0);
      }
    __builtin_amdgcn_s_setprio(0);
    // A k1 fragments from As[t&1]: not overwritten this tile, no barrier
#pragma unroll
    for (int i = 0; i < 4; i++) alo[i] = lds_frag(Ah, i * 16 + ln, 1, lg);
#pragma unroll
    for (int i = 0; i < 4; i++) ahi[i] = lds_frag(Ah, 64 + i * 16 + ln, 1, lg);
    __builtin_amdgcn_s_setprio(1);
#pragma unroll
    for (int mi = 0; mi < 4; mi++)
#pragma unroll
      for (int ni = 0; ni < 4; ni++) {
        acc[mi][ni] = __builtin_amdgcn_mfma_f32_16x16x32_f16(alo[mi], b1[ni], acc[mi][ni], 0, 0, 0);
        acc[mi + 4][ni] = __builtin_amdgcn_mfma_f32_16x16x32_f16(ahi[mi], b1[ni], acc[mi + 4][ni], 0, 0, 0);
      }
    __builtin_amdgcn_s_setprio(0);
    asm volatile("" ::: "memory");
  }

  int row0 = by * 256 + wm * 128;
  int col0 = bx * 256 + wn * 64;
#pragma unroll
  for (int mi = 0; mi < 8; mi++)
#pragma unroll
    for (int ni = 0; ni < 4; ni++)
#pragma unroll
      for (int r4 = 0; r4 < 4; r4++) {
        int row = row0 + mi * 16 + lg * 4 + r4;
        int col = col0 + ni * 16 + ln;
        float o = acc[mi][ni][r4];
        if constexpr (sizeof(CT) == 2) {
          float oo = __shfl_xor(o, 1);
          if (!(ln & 1)) {
            f16x2 pp; pp[0] = (f16)o; pp[1] = (f16)oo;
            *(f16x2*)(&C[(size_t)row * ldc + col]) = pp;
          }
        } else {
          C[(size_t)row * ldc + col] = o;
        }
      }
}

__global__ __launch_bounds__(256) void rope_table(float2* __restrict__ tab, const int* __restrict__ st) {
  int i = blockIdx.x * 256 + threadIdx.x;  // S*64 entries
  int s = i >> 6, j = i & 63;
  float theta = powf(10000.f, -(float)j / 64.f);
  float ang = (float)(s + st[0]) * theta;
  tab[i] = make_float2(cosf(ang), sinf(ang));
}

// RoPE over the K columns (2048..4095) of the fused qkv buffer, in place.
__global__ __launch_bounds__(256) void rope_apply_k(f16* __restrict__ QKV, const float2* __restrict__ tab,
                                                    long npairs) {
  long i0 = (long)blockIdx.x * 256 + threadIdx.x;
  long stride = (long)gridDim.x * 256;
  for (long p = i0; p < npairs; p += stride) {
    long row = p >> 10;            // 1024 K-pairs per row
    int jp = (int)(p & 1023);
    int s = (int)(row & (S_ - 1));
    float2 cs = tab[s * 64 + (jp & 63)];
    f16* px = QKV + row * QKV_ST + 2048 + 2 * jp;
    f16x2 v = *(const f16x2*)px;
    float xe = (float)v[0], xo = (float)v[1];
    float re = xe * cs.x - xo * cs.y;
    float ro = xe * cs.y + xo * cs.x;
    f16x2 o; o[0] = (f16)re; o[1] = (f16)ro;
    *(f16x2*)px = o;
  }
}

// V (qkv cols 4096+) -> VT2 fragment-linear with the ZERO-SHUFFLE k<->kv
// mapping: per (bh, kv-tile t, nj, kk) one 1KB chunk; lane l=(lg*16+ln),
// element e owns V[d = nj*16 + ln][kv = t*64 + 16*(2kk+(e>>2)) + 4lg + (e&3)].
// Sigma matches QK^T's lane-local layout so attn's PV B-operand is a pure
// in-register pack. Both A (V) and B (P) use this sigma.
__global__ __launch_bounds__(256) void vtrans2(const f16* __restrict__ QKV, f16* __restrict__ VT2) {
  __shared__ alignas(16) f16 tile[64 * 128];  // [kv][d], 16B-chunk XOR-swizzled
  int t = blockIdx.x, bh = blockIdx.y, b = bh >> 4, h = bh & 15;
  int tid = threadIdx.x, w = tid >> 6, l = tid & 63, lg = l >> 4, ln = l & 15;
  const f16* src = QKV + (size_t)(b * S_ + t * 64) * QKV_ST + 4096 + h * HD_;
#pragma unroll
  for (int i = 0; i < 4; i++) {
    int idx = i * 256 + tid;            // 16B-unit index
    int r = idx >> 4, c8 = idx & 15;
    int c8s = c8 ^ ((r >> 3) & 3);      // swizzle: both sides use same XOR
    *(f16x8*)(&tile[r * 128 + c8s * 8]) = *(const f16x8*)(src + (size_t)r * QKV_ST + c8 * 8);
  }
  __syncthreads();
  f16* dst = VT2 + (size_t)(bh * 32 + t) * 16 * 512;
#pragma unroll
  for (int ci = 0; ci < 4; ci++) {
    int c = w * 4 + ci;                 // chunk = nj*2 + kk
    int nj = c >> 1, kk = c & 1;
    f16x8 v;
#pragma unroll
    for (int e = 0; e < 8; e++) {
      int r = 16 * (2 * kk + (e >> 2)) + 4 * lg + (e & 3);  // sigma(k-slot)
      int col = nj * 16 + ln;
      int c8s = (col >> 3) ^ ((r >> 3) & 3);
      v[e] = tile[r * 128 + c8s * 8 + (col & 7)];
    }
    *(f16x8*)(dst + (size_t)c * 512 + l * 8) = v;
  }
}

// flash attention, causal. 8 waves x 16 q-rows (QBLK=128), KV tile = 64,
// TWO KV-TILES PER BARRIER PERIOD: kls[2][2][64*128] (64KB, 2 blocks/CU).
// R11 config (best measured attn, 127.4us). SWAPPED QK^T; lane-local
// softmax; ZERO-SHUFFLE PV (VT2 sigma); Q-RoPE fused into Q load; V
// chunks 0-7 after QK^T; UNIFORM blocks via causal pairing (15-u, u).
// Q/K read from fused qkv (stride 6144); O written back into Q columns.
// lsum quad-reduce deferred to epilogue. log2 scores; T13 defer-max THR=8.
__global__ __launch_bounds__(512, 4) void attn(f16* __restrict__ QKV, const f16* __restrict__ VT2,
                                               const float2* __restrict__ tab) {
  __shared__ alignas(16) f16 kls[2][2][64 * 128];
  int id = blockIdx.x;                   // 512 blocks
  int r8 = id & 7, j = id >> 3;          // j: 0..63 per XCD-residue
  int u = j & 7, g = j >> 3;             // u: pair id, g: bh group 0..7
  int bh = r8 + (g << 3);                // 8 bh's per XCD residue, bh-major
  int b = bh >> 4, h = bh & 15;
  int tid = threadIdx.x, w = tid >> 6, l = tid & 63, lg = l >> 4, ln = l & 15;

  const float QSCALE = 0.12751744910173355f;  // log2(e)/sqrt(128)
  const f16* kp = QKV + (size_t)(b * S_) * QKV_ST + 2048 + h * HD_;
  const f16* vp2 = VT2 + (size_t)bh * 32 * 16 * 512;

  auto stageK = [&](int buf, int half, int kv0) {
#pragma unroll
    for (int jj = 0; jj < 2; jj++) {
      int i = jj * 8 + w;
      int byte = i * 1024 + 16 * l;
      int r = byte >> 8;                       // row 0..63
      int c = (((byte >> 4) & 15) - r) & 15;   // inverse additive swizzle
      gl_lds16(kp + (size_t)(kv0 + r) * QKV_ST + c * 8, (char*)kls[buf][half] + i * 1024);
    }
  };

#pragma unroll 1
  for (int pi = 0; pi < 2; pi++) {
    int qsel = pi ? u : 15 - u;          // heavy pass first (K range in L2)
    int q0 = qsel << 7;
    int qrow = q0 + w * 16 + ln;         // this lane's q row (output column)
    f16* qp = QKV + (size_t)(b * S_ + qrow) * QKV_ST + h * HD_;
    const float2* tq = tab + (size_t)qrow * 64;
    f16x8 qf[4];
#pragma unroll
    for (int kc = 0; kc < 4; kc++) {
      f16x8 q = *(const f16x8*)(qp + kc * 32 + lg * 8);
#pragma unroll
      for (int p = 0; p < 4; p++) {
        float2 cs = tq[kc * 16 + lg * 4 + p];
        float e0 = (float)q[2 * p], e1 = (float)q[2 * p + 1];
        q[2 * p] = (f16)((e0 * cs.x - e1 * cs.y) * QSCALE);
        q[2 * p + 1] = (f16)((e0 * cs.y + e1 * cs.x) * QSCALE);
      }
      qf[kc] = q;
    }

    float m = -1e30f, lsum = 0.f;        // lsum: LANE-LOCAL partial
    f32x4 oacc[8] = {};                  // O^T[d = nj*16 + lg*4 + r4][q = ln]

    int np = qsel + 1;                   // periods; nt64 = 2*qsel+2 tiles
    int nt64 = 2 * qsel + 2;
    if (pi) __syncthreads();             // kls readers from prev pass done
    stageK(0, 0, 0);                     // prologue: period 0 (tiles 0,1)
    stageK(0, 1, 64);
#pragma unroll 1
    for (int p = 0; p < np; p++) {
      __syncthreads();  // drains period-p staging; all waves done with buf
      if (p + 1 < np) {
        stageK((p + 1) & 1, 0, (2 * p + 2) << 6);
        stageK((p + 1) & 1, 1, (2 * p + 3) << 6);
      }
#pragma unroll 1
      for (int ii = 0; ii < 2; ii++) {
        int t = 2 * p + ii;
        int kv0 = t << 6;
        // wave-uniform skip: this wave's rows all precede the tile
        if (kv0 > q0 + w * 16 + 15) continue;
        const f16* kb = kls[p & 1][ii];
        const f16* vt = vp2 + (size_t)t * 16 * 512;

        // S^T = K Q^T: sf[ni][r4] = S[kv = kv0 + ni*16 + lg*4 + r4][q = ln]
        f32x4 sf[4];
        __builtin_amdgcn_s_setprio(1);
#pragma unroll
        for (int ni = 0; ni < 4; ni++) {
          int n = ni * 16 + ln;
          f32x4 s = {0.f, 0.f, 0.f, 0.f};
#pragma unroll
          for (int kc = 0; kc < 4; kc++) {
            int mch = kc * 4 + lg;
            f16x8 kf = *(const f16x8*)(&kb[n * 128 + (((mch + n) & 15) << 3)]);
            s = __builtin_amdgcn_mfma_f32_16x16x32_f16(kf, qf[kc], s, 0, 0, 0);
          }
          sf[ni] = s;
        }
        __builtin_amdgcn_s_setprio(0);

        // V chunks 0-7 issued now; latency hides under mask+softmax
        f16x8 vfa[8];
#pragma unroll
        for (int c = 0; c < 8; c++) vfa[c] = *(const f16x8*)(vt + c * 512 + l * 8);

        if (t >= nt64 - 2) {  // only the two diagonal-adjacent tiles mask
#pragma unroll
          for (int ni = 0; ni < 4; ni++) {
            int kvg = kv0 + ni * 16 + lg * 4;
#pragma unroll
            for (int r4 = 0; r4 < 4; r4++)
              if (kvg + r4 > qrow) sf[ni][r4] = -1e30f;
          }
        }
        // online softmax (log2 domain), lane-local + 2 shfl (max only)
        float pm = fmaxf(fmaxf(fmaxf(sf[0][0], sf[0][1]), fmaxf(sf[0][2], sf[0][3])),
                         fmaxf(fmaxf(sf[1][0], sf[1][1]), fmaxf(sf[1][2], sf[1][3])));
        pm = fmaxf(pm, fmaxf(fmaxf(fmaxf(sf[2][0], sf[2][1]), fmaxf(sf[2][2], sf[2][3])),
                             fmaxf(fmaxf(sf[3][0], sf[3][1]), fmaxf(sf[3][2], sf[3][3]))));
        pm = fmaxf(pm, __shfl_xor(pm, 16));
        pm = fmaxf(pm, __shfl_xor(pm, 32));
        // T13 defer-max: keep old m while tile max hasn't outgrown it by >8
        float scl = 1.f;
        bool defer = __all(pm <= m + 8.f);
        if (!defer) {
          float mn = fmaxf(m, pm);
          scl = __builtin_amdgcn_exp2f(m - mn);
          m = mn;
        }
        float rsum = 0.f;
#pragma unroll
        for (int ni = 0; ni < 4; ni++)
#pragma unroll
          for (int r4 = 0; r4 < 4; r4++) {
            float pv = __builtin_amdgcn_exp2f(sf[ni][r4] - m);
            sf[ni][r4] = pv;
            rsum += pv;
          }
        lsum = lsum * scl + rsum;  // lane-local; cross-lane in epilogue

        // rescale O^T (skipped on defer tiles)
        if (!defer) {
#pragma unroll
          for (int nj = 0; nj < 8; nj++)
#pragma unroll
            for (int r4 = 0; r4 < 4; r4++) oacc[nj][r4] *= scl;
        }

        // ZERO-SHUFFLE pack: pa[kk] = [sf[2kk][0..3], sf[2kk+1][0..3]]
        f16x8 pa[2];
#pragma unroll
        for (int kk = 0; kk < 2; kk++) {
          i32x4 wv;
          wv.x = cvt_pk_i32(sf[2 * kk][0], sf[2 * kk][1]);
          wv.y = cvt_pk_i32(sf[2 * kk][2], sf[2 * kk][3]);
          wv.z = cvt_pk_i32(sf[2 * kk + 1][0], sf[2 * kk + 1][1]);
          wv.w = cvt_pk_i32(sf[2 * kk + 1][2], sf[2 * kk + 1][3]);
          pa[kk] = __builtin_bit_cast(f16x8, wv);
        }

        __builtin_amdgcn_s_setprio(1);
        // PV first half: nj 0-3 from pre-issued vfa (chunk = nj*2+kk)
#pragma unroll
        for (int kk = 0; kk < 2; kk++)
#pragma unroll
          for (int nj = 0; nj < 4; nj++)
            oacc[nj] = __builtin_amdgcn_mfma_f32_16x16x32_f16(vfa[nj * 2 + kk], pa[kk], oacc[nj], 0, 0, 0);
        // PV second half: nj 4-7, in-loop batches of 4
#pragma unroll
        for (int njb = 0; njb < 2; njb++) {
          f16x8 vf[4];
#pragma unroll
          for (int jj = 0; jj < 2; jj++)
#pragma unroll
            for (int kk = 0; kk < 2; kk++)
              vf[jj * 2 + kk] = *(const f16x8*)(vt + (size_t)(((4 + njb * 2 + jj) * 2 + kk) * 512) + l * 8);
#pragma unroll
          for (int kk = 0; kk < 2; kk++)
#pragma unroll
            for (int jj = 0; jj < 2; jj++)
              oacc[4 + njb * 2 + jj] = __builtin_amdgcn_mfma_f32_16x16x32_f16(
                  vf[jj * 2 + kk], pa[kk], oacc[4 + njb * 2 + jj], 0, 0, 0);
        }
        __builtin_amdgcn_s_setprio(0);
      }
    }

    // per-pass epilogue: quad-reduce lane-local lsum; write O into the Q
    // columns of qkv (this block's own rows, already consumed).
    lsum += __shfl_xor(lsum, 16);
    lsum += __shfl_xor(lsum, 32);
    float inv = 1.f / lsum;
#pragma unroll
    for (int nj = 0; nj < 8; nj++) {
      f16x4v ov;
#pragma unroll
      for (int r4 = 0; r4 < 4; r4++) ov[r4] = (f16)(oacc[nj][r4] * inv);
      *(f16x4v*)(qp + nj * 16 + lg * 4) = ov;
    }
  }
}

extern "C" void kernel_launch(void* const* d_in, const int* in_sizes, int n_in,
                              void* d_out, int out_size, void* d_ws, size_t ws_size,
                              hipStream_t stream) {
  (void)in_sizes; (void)n_in; (void)out_size; (void)ws_size;
  const float* x = (const float*)d_in[0];
  // d_in[1] = mask (causal, reproduced analytically)
  const float* Wq = (const float*)d_in[2];
  const float* Wk = (const float*)d_in[3];
  const float* Wv = (const float*)d_in[4];
  const float* Wo = (const float*)d_in[5];
  const int* stp = (const int*)d_in[6];
  float* out = (float*)d_out;

  const size_t MS = (size_t)B_ * S_;  // 8192
  f16* xh = (f16*)d_ws;                         // 32MB
  f16* wqt = xh + MS * D_;                      // wqt|wkt|wvt|wot contiguous, 32MB
  f16* wot = wqt + (size_t)3 * D_ * D_;
  f16* qkv = wot + (size_t)D_ * D_;             // 8192 x 6144 f16, ~100MB
  float2* tab = (float2*)(qkv + MS * (size_t)QKV_ST);
  f16* vt2 = xh;  // reuse: x consumed after the QKV GEMMs

  cvt_f32_to_f16<<<16384, 256, 0, stream>>>(x, xh, (long)(MS * D_));
  wtrans4<<<dim3(4096, 4), 256, 0, stream>>>(Wq, Wk, Wv, Wo, wqt);
  // ONE 768-block launch = 3 subgroup GEMMs (Q,K,V) sharing A in L2.
  gemm8<f16><<<768, 512, 0, stream>>>(xh, wqt, qkv, 8192, 2048, 2048, 2048, QKV_ST,
                                      (long)D_ * D_, 2048);
  rope_table<<<512, 256, 0, stream>>>(tab, stp);
  // K roped in place (qkv cols 2048-4095); Q-RoPE fused into attn.
  rope_apply_k<<<4096, 256, 0, stream>>>(qkv, tab, (long)(MS * 1024));
  vtrans2<<<dim3(32, 64), 256, 0, stream>>>(qkv, vt2);
  // attn reads Q/K from qkv, writes O into qkv's Q columns
  attn<<<512, 512, 0, stream>>>(qkv, vt2, tab);
  // Wo GEMM: A = qkv Q-columns (lda=6144)
  gemm8<float><<<256, 512, 0, stream>>>(qkv, wot, out, 8192, 2048, 2048, QKV_ST, 2048, 0, 0);
}